// Round 11
// baseline (353.801 us; speedup 1.0000x reference)
//
#include <hip/hip_runtime.h>
#include <hip/hip_bf16.h>
#include <cstdint>
#include <cstddef>

#define NNODES 50000
#define NEDGES 800000
#define D_IN   128
#define D_H    256
#define D_OUT  64
#define BSH    9
#define BKN    (1 << BSH)                             // 512 nodes per bucket
#define NBKT   ((NNODES + BKN - 1) / BKN)             // 98
#define MAXB   12288                                  // cap per bucket (45 sigma)
#define CHUNK  2048
#define QMAX   32639.0f                               // 127*256+127: i8-splittable int16 range

typedef __attribute__((ext_vector_type(8))) short bf16x8;
typedef __attribute__((ext_vector_type(4))) float f32x4;
typedef __attribute__((ext_vector_type(4))) int   i32x4;

__device__ __forceinline__ unsigned short f2bf(float f) {
    unsigned u = __builtin_bit_cast(unsigned, f);
    unsigned r = (u + 0x7FFFu + ((u >> 16) & 1u)) >> 16;
    return (unsigned short)r;
}
__device__ __forceinline__ float bf2f(unsigned short h) {
    unsigned u = ((unsigned)h) << 16;
    return __builtin_bit_cast(float, u);
}

// ---------------- CSR build: bin -> bucket scan -> fused per-bucket CSR ----------------

__global__ __launch_bounds__(256) void k_bin(const int* __restrict__ adjA, const int* __restrict__ adjB,
                                             int* __restrict__ bcnt, unsigned* __restrict__ binned, int e) {
    __shared__ int h[NBKT], pfx[NBKT], put[NBKT], gbase[NBKT];
    __shared__ unsigned stage[CHUNK];
    const int g = blockIdx.y;
    const int* srcp = g ? adjB : adjA;
    const int* dstp = srcp + e;
    unsigned* outp = binned + (size_t)g * NBKT * MAXB;
    int* bc = bcnt + g * NBKT;
    const int tid = threadIdx.x;
    const int base = blockIdx.x * CHUNK;
    const int nrem = min(CHUNK, e - base);
    if (nrem <= 0) return;

    for (int t = tid; t < NBKT; t += 256) { h[t] = 0; put[t] = 0; }
    __syncthreads();

    unsigned pv[8];
    int bv[8];
    #pragma unroll
    for (int q = 0; q < 8; ++q) {
        int i = base + q * 256 + tid;
        bv[q] = -1;
        if (i < e) {
            int s = srcp[i];
            int d = dstp[i];
            pv[q] = ((unsigned)d << 16) | (unsigned)s;
            bv[q] = d >> BSH;
            atomicAdd(&h[bv[q]], 1);
        }
    }
    __syncthreads();
    if (tid == 0) {
        int r = 0;
        for (int k = 0; k < NBKT; ++k) { pfx[k] = r; r += h[k]; }
    }
    __syncthreads();
    #pragma unroll
    for (int q = 0; q < 8; ++q) {
        if (bv[q] >= 0) {
            int p = pfx[bv[q]] + atomicAdd(&put[bv[q]], 1);
            stage[p] = pv[q];
        }
    }
    __syncthreads();
    if (tid < NBKT && h[tid] > 0) gbase[tid] = atomicAdd(&bc[tid], h[tid]);
    __syncthreads();
    for (int idx = tid; idx < nrem; idx += 256) {
        unsigned v = stage[idx];
        int bb = v >> (16 + BSH);
        outp[(size_t)bb * MAXB + gbase[bb] + (idx - pfx[bb])] = v;
    }
}

__global__ void k_bktscan(const int* __restrict__ bcnt, int* __restrict__ bbase,
                          int* __restrict__ rp1, int* __restrict__ rp2) {
    __shared__ int s[2][NBKT];
    int t = threadIdx.x;
    if (t < NBKT) s[0][t] = bcnt[t];
    else if (t < 2 * NBKT) s[1][t - NBKT] = bcnt[t];
    __syncthreads();
    if (t < 2) {
        int r = 0;
        for (int k = 0; k < NBKT; ++k) { int v = s[t][k]; s[t][k] = r; r += v; }
    }
    __syncthreads();
    if (t < NBKT) bbase[t] = s[0][t];
    else if (t < 2 * NBKT) bbase[t] = s[1][t - NBKT];
    if (t == 0) { rp1[NNODES] = NEDGES; rp2[NNODES] = NEDGES; }
}

__global__ __launch_bounds__(256) void k_csr_bucket(const unsigned* __restrict__ binned,
                                                    const int* __restrict__ bcnt, const int* __restrict__ bbase,
                                                    int* __restrict__ rp1, int* __restrict__ rp2,
                                                    float* __restrict__ dinv1, float* __restrict__ dinv2,
                                                    int* __restrict__ col1, int* __restrict__ col2, int n) {
    __shared__ int lc[BKN];
    __shared__ int loff[BKN];
    __shared__ int ps[256];
    __shared__ int srt[MAXB];
    const int g = blockIdx.y;
    const int b = blockIdx.x;
    const unsigned* in = binned + (size_t)g * NBKT * MAXB + (size_t)b * MAXB;
    int* rp = g ? rp2 : rp1;
    float* dinv = g ? dinv2 : dinv1;
    int* col = g ? col2 : col1;
    const int nb = bcnt[g * NBKT + b];
    const int base0 = bbase[g * NBKT + b];
    const int nodebase = b << BSH;
    const int tid = threadIdx.x;

    for (int t = tid; t < BKN; t += 256) lc[t] = 0;
    __syncthreads();
    for (int t = tid; t < nb; t += 256)
        atomicAdd(&lc[(in[t] >> 16) & (BKN - 1)], 1);
    __syncthreads();
    int c0 = lc[2 * tid], c1 = lc[2 * tid + 1];
    int pair = c0 + c1;
    int sum = pair;
    ps[tid] = pair;
    __syncthreads();
    #pragma unroll
    for (int off = 1; off < 256; off <<= 1) {
        int u = (tid >= off) ? ps[tid - off] : 0;
        __syncthreads();
        sum += u;
        ps[tid] = sum;
        __syncthreads();
    }
    int excl = sum - pair;
    loff[2 * tid] = excl;
    loff[2 * tid + 1] = excl + c0;
    __syncthreads();
    for (int t = tid; t < BKN; t += 256) {
        int node = nodebase + t;
        if (node < n) {
            rp[node] = base0 + loff[t];
            dinv[node] = rsqrtf((float)(lc[t] + 1));
        }
    }
    __syncthreads();
    for (int t = tid; t < nb; t += 256) {
        unsigned v = in[t];
        int pos = atomicAdd(&loff[(v >> 16) & (BKN - 1)], 1);
        srt[pos] = (int)(v & 0xFFFFu);
    }
    __syncthreads();
    for (int t = tid; t < nb; t += 256) col[base0 + t] = srt[t];
}

// ---------------- quantize: fp32 rows -> int16 rows + per-row scale ----------------

template<int F, bool PRESCALE>
__global__ __launch_bounds__(256) void k_quant(const float* __restrict__ in, const float* __restrict__ dscale,
                                               short* __restrict__ q, float* __restrict__ qs, int n) {
    constexpr int VPT = F / 64;
    const int lane = threadIdx.x & 63;
    const int i = blockIdx.x * 4 + (threadIdx.x >> 6);
    if (i >= n) return;
    float v[VPT];
    const float* p = in + (size_t)i * F + lane * VPT;
    if constexpr (VPT == 4) { float4 t = *(const float4*)p; v[0] = t.x; v[1] = t.y; v[2] = t.z; v[3] = t.w; }
    else if constexpr (VPT == 2) { float2 t = *(const float2*)p; v[0] = t.x; v[1] = t.y; }
    else v[0] = *p;
    if constexpr (PRESCALE) {
        float d = dscale[i];
        #pragma unroll
        for (int c = 0; c < VPT; ++c) v[c] *= d;
    }
    float m = 0.f;
    #pragma unroll
    for (int c = 0; c < VPT; ++c) m = fmaxf(m, fabsf(v[c]));
    #pragma unroll
    for (int off = 32; off > 0; off >>= 1) m = fmaxf(m, __shfl_xor(m, off));
    float inv = (m > 0.f) ? 32767.0f / m : 0.f;
    short* qp = q + (size_t)i * F + lane * VPT;
    if constexpr (VPT == 4) {
        short4 o;
        o.x = (short)__float2int_rn(v[0] * inv);
        o.y = (short)__float2int_rn(v[1] * inv);
        o.z = (short)__float2int_rn(v[2] * inv);
        o.w = (short)__float2int_rn(v[3] * inv);
        *(short4*)qp = o;
    } else if constexpr (VPT == 2) {
        short2 o;
        o.x = (short)__float2int_rn(v[0] * inv);
        o.y = (short)__float2int_rn(v[1] * inv);
        *(short2*)qp = o;
    } else {
        *qp = (short)__float2int_rn(v[0] * inv);
    }
    if (lane == 0) qs[i] = m * (1.0f / 32767.0f);
}

// ---------------- Aggregation over int16-quantized prescaled input ----------------
// OUTM 0: emit per-row-quantized i8 hi/lo planes (A8h | A8l, each [n][F]) + qs_out
// OUTM 1: fp32 + bias (final output)

template<int F, int OUTM>
__global__ __launch_bounds__(256) void k_agg3(const short* __restrict__ q, const float* __restrict__ qs,
                                              const int* __restrict__ rp, const int* __restrict__ col,
                                              const float* __restrict__ dinv, const float* __restrict__ bias,
                                              void* __restrict__ outv, float* __restrict__ qs_out, int n) {
    constexpr int VPT = F / 64;
    const int lane = threadIdx.x & 63;
    const int i = blockIdx.x * 4 + (threadIdx.x >> 6);
    if (i >= n) return;
    const short* ql = q + lane * VPT;
    float acc[VPT];
    #pragma unroll
    for (int c = 0; c < VPT; ++c) acc[c] = 0.f;

    int k = rp[i], end = rp[i + 1];

    auto body1 = [&](int j) {
        float s = qs[j];
        const short* pj = ql + (size_t)j * F;
        if constexpr (VPT == 4) {
            short4 v = *(const short4*)pj;
            acc[0] += s * (float)v.x; acc[1] += s * (float)v.y;
            acc[2] += s * (float)v.z; acc[3] += s * (float)v.w;
        } else if constexpr (VPT == 2) {
            short2 v = *(const short2*)pj;
            acc[0] += s * (float)v.x; acc[1] += s * (float)v.y;
        } else {
            acc[0] += s * (float)(*pj);
        }
    };

    body1(i);  // self loop
    for (; k + 4 <= end; k += 4) {
        int j0 = col[k], j1 = col[k + 1], j2 = col[k + 2], j3 = col[k + 3];
        float s0 = qs[j0], s1 = qs[j1], s2 = qs[j2], s3 = qs[j3];
        if constexpr (VPT == 4) {
            short4 v0 = *(const short4*)(ql + (size_t)j0 * F);
            short4 v1 = *(const short4*)(ql + (size_t)j1 * F);
            short4 v2 = *(const short4*)(ql + (size_t)j2 * F);
            short4 v3 = *(const short4*)(ql + (size_t)j3 * F);
            acc[0] += s0 * (float)v0.x + s1 * (float)v1.x + s2 * (float)v2.x + s3 * (float)v3.x;
            acc[1] += s0 * (float)v0.y + s1 * (float)v1.y + s2 * (float)v2.y + s3 * (float)v3.y;
            acc[2] += s0 * (float)v0.z + s1 * (float)v1.z + s2 * (float)v2.z + s3 * (float)v3.z;
            acc[3] += s0 * (float)v0.w + s1 * (float)v1.w + s2 * (float)v2.w + s3 * (float)v3.w;
        } else if constexpr (VPT == 2) {
            short2 v0 = *(const short2*)(ql + (size_t)j0 * F);
            short2 v1 = *(const short2*)(ql + (size_t)j1 * F);
            short2 v2 = *(const short2*)(ql + (size_t)j2 * F);
            short2 v3 = *(const short2*)(ql + (size_t)j3 * F);
            acc[0] += s0 * (float)v0.x + s1 * (float)v1.x + s2 * (float)v2.x + s3 * (float)v3.x;
            acc[1] += s0 * (float)v0.y + s1 * (float)v1.y + s2 * (float)v2.y + s3 * (float)v3.y;
        } else {
            float v0 = (float)ql[(size_t)j0 * F];
            float v1 = (float)ql[(size_t)j1 * F];
            float v2 = (float)ql[(size_t)j2 * F];
            float v3 = (float)ql[(size_t)j3 * F];
            acc[0] += s0 * v0 + s1 * v1 + s2 * v2 + s3 * v3;
        }
    }
    for (; k < end; ++k) body1(col[k]);

    float di = dinv[i];
    if constexpr (OUTM == 0) {
        float vals[VPT];
        float m = 0.f;
        #pragma unroll
        for (int c = 0; c < VPT; ++c) { vals[c] = acc[c] * di; m = fmaxf(m, fabsf(vals[c])); }
        #pragma unroll
        for (int off = 32; off > 0; off >>= 1) m = fmaxf(m, __shfl_xor(m, off));
        float inv = (m > 0.f) ? QMAX / m : 0.f;
        unsigned ph = 0, pl = 0;
        #pragma unroll
        for (int c = 0; c < VPT; ++c) {
            int qv = __float2int_rn(vals[c] * inv);
            int ah = (qv + 128) >> 8;
            int al = qv - (ah << 8);
            ph |= (unsigned)(ah & 0xFF) << (8 * c);
            pl |= (unsigned)(al & 0xFF) << (8 * c);
        }
        unsigned char* o8h = (unsigned char*)outv;
        unsigned char* o8l = o8h + (size_t)n * F;
        if constexpr (VPT == 4) {
            *(unsigned*)(o8h + (size_t)i * F + lane * 4) = ph;
            *(unsigned*)(o8l + (size_t)i * F + lane * 4) = pl;
        } else if constexpr (VPT == 2) {
            *(unsigned short*)(o8h + (size_t)i * F + lane * 2) = (unsigned short)ph;
            *(unsigned short*)(o8l + (size_t)i * F + lane * 2) = (unsigned short)pl;
        } else {
            o8h[(size_t)i * F + lane] = (unsigned char)ph;
            o8l[(size_t)i * F + lane] = (unsigned char)pl;
        }
        if (lane == 0) qs_out[i] = m * (1.0f / QMAX);
    } else {
        float* o = (float*)outv + (size_t)i * F + lane * VPT;
        #pragma unroll
        for (int c = 0; c < VPT; ++c) o[c] = acc[c] * di + bias[lane * VPT + c];
    }
}

// ---------------- weight preconvert: bf16 hi/lo path (L1w, L2w, W3) ----------------

__device__ __forceinline__ void wconv1(const float* __restrict__ W, unsigned short* __restrict__ Th,
                                       unsigned short* __restrict__ Tl, int idx, int K, int Nc) {
    int k = idx / Nc, n = idx - k * Nc;
    float v = W[idx];
    unsigned short h = f2bf(v);
    unsigned short l = f2bf(v - bf2f(h));
    Th[(size_t)n * K + k] = h;
    Tl[(size_t)n * K + k] = l;
}

__global__ void k_wconv_all(const float* L1w, const float* L2w, const float* W3,
                            unsigned short* L1h, unsigned short* L1l, unsigned short* L2h, unsigned short* L2l,
                            unsigned short* W3h, unsigned short* W3l) {
    int idx = blockIdx.x * blockDim.x + threadIdx.x;
    if (idx < 32768)        wconv1(L1w, L1h, L1l, idx, D_H, D_IN);
    else if (idx < 65536)   wconv1(L2w, L2h, L2l, idx - 32768, D_IN, D_H);
    else if (idx < 81920)   wconv1(W3, W3h, W3l, idx - 65536, D_H, D_OUT);
}

// ---------------- weight preconvert: int16 per-col scale -> i8 hi/lo planes (W1, W2) ----------------
// W [K][256] fp32 -> B8h/B8l [256][K] i8, ws[256]. One wave per column.

__global__ __launch_bounds__(256) void k_wconv_i8(const float* __restrict__ W1, const float* __restrict__ W2,
        signed char* __restrict__ B1h, signed char* __restrict__ B1l,
        signed char* __restrict__ B2h, signed char* __restrict__ B2l,
        float* __restrict__ ws1, float* __restrict__ ws2) {
    const int c4 = blockIdx.x * 4 + (threadIdx.x >> 6);
    const int lane = threadIdx.x & 63;
    const float* W; signed char *Bh, *Bl; float* ws; int K, c;
    if (c4 < 256) { W = W1; Bh = B1h; Bl = B1l; ws = ws1; K = D_IN; c = c4; }
    else          { W = W2; Bh = B2h; Bl = B2l; ws = ws2; K = D_H;  c = c4 - 256; }
    float m = 0.f;
    for (int k = lane; k < K; k += 64) m = fmaxf(m, fabsf(W[(size_t)k * D_H + c]));
    #pragma unroll
    for (int off = 32; off > 0; off >>= 1) m = fmaxf(m, __shfl_xor(m, off));
    float inv = (m > 0.f) ? QMAX / m : 0.f;
    for (int k = lane; k < K; k += 64) {
        int qv = __float2int_rn(W[(size_t)k * D_H + c] * inv);
        int ah = (qv + 128) >> 8;
        int al = qv - (ah << 8);
        Bh[(size_t)c * K + k] = (signed char)ah;
        Bl[(size_t)c * K + k] = (signed char)al;
    }
    if (lane == 0) ws[c] = m * (1.0f / QMAX);
}

// ---------------- i8 exact-split MFMA GEMM ----------------
// C = (qs[r]*ws[c]) * sum_k Aq[r][k]*Bq[k][c], Aq/Bq int16 = ah*256+al (i8 planes).
// 4 exact products via mfma_i32_16x16x64_i8. Block 128x64, 4 waves, PADB=68 (17 dw odd).
// OUTM 1: fp32 * dscale[row]; OUTM 2: bf16 hi/lo planes [M][2N].

template<bool RELU, bool BIAS, int OUTM>
__global__ __launch_bounds__(256) void k_gemm_i8(const unsigned char* __restrict__ A8,
        const float* __restrict__ qsr,
        const signed char* __restrict__ B8h, const signed char* __restrict__ B8l,
        const float* __restrict__ wsc,
        const float* __restrict__ bias, const float* __restrict__ dscale,
        void* __restrict__ Cv, int M, int K, int Nc, int ncb) {
    constexpr int PADB = 68;
    __shared__ unsigned char As_h[128][PADB];
    __shared__ unsigned char As_l[128][PADB];
    __shared__ unsigned char Bs_h[64][PADB];
    __shared__ unsigned char Bs_l[64][PADB];

    const int nwg = gridDim.x;
    const int b = blockIdx.x;
    const int q8 = nwg >> 3, r8 = nwg & 7;
    const int xcd = b & 7;
    const int swz = (xcd < r8 ? xcd * (q8 + 1) : r8 * (q8 + 1) + (xcd - r8) * q8) + (b >> 3);
    const int row0 = (swz / ncb) * 128;
    const int col0 = (swz % ncb) * 64;

    const int tid = threadIdx.x;
    const int lane = tid & 63;
    const int wv = tid >> 6;

    i32x4 acc_hh[2][4], acc_mm[2][4], acc_ll[2][4];
    #pragma unroll
    for (int m = 0; m < 2; ++m)
        #pragma unroll
        for (int n = 0; n < 4; ++n) {
            acc_hh[m][n] = (i32x4)(0);
            acc_mm[m][n] = (i32x4)(0);
            acc_ll[m][n] = (i32x4)(0);
        }

    // A staging: 2 threads per row, 32 bytes each per plane per kt
    const int srow = tid >> 1;
    const int skh = (tid & 1) * 32;
    int arow = row0 + srow;
    if (arow >= M) arow = M - 1;
    const unsigned char* aph = A8 + (size_t)arow * K + skh;
    const unsigned char* apl = aph + (size_t)M * K;

    // B staging: 4 threads per col, 16 bytes each per plane per kt
    const int bn = tid >> 2;
    const int bko = (tid & 3) * 16;
    const signed char* bph = B8h + (size_t)(col0 + bn) * K + bko;
    const signed char* bpl = B8l + (size_t)(col0 + bn) * K + bko;

    const int fr = lane & 15;
    const int fko = (lane >> 4) * 16;   // byte offset of this lane's K-chunk

    const int nk = K >> 6;
    for (int kt = 0; kt < nk; ++kt) {
        uint4 ah0 = *(const uint4*)(aph + kt * 64);
        uint4 ah1 = *(const uint4*)(aph + kt * 64 + 16);
        uint4 al0 = *(const uint4*)(apl + kt * 64);
        uint4 al1 = *(const uint4*)(apl + kt * 64 + 16);
        uint4 bh0 = *(const uint4*)(bph + kt * 64);
        uint4 bl0 = *(const uint4*)(bpl + kt * 64);

        __syncthreads();

        *(uint4*)&As_h[srow][skh] = ah0;
        *(uint4*)&As_h[srow][skh + 16] = ah1;
        *(uint4*)&As_l[srow][skh] = al0;
        *(uint4*)&As_l[srow][skh + 16] = al1;
        *(uint4*)&Bs_h[bn][bko] = bh0;
        *(uint4*)&Bs_l[bn][bko] = bl0;

        __syncthreads();

        i32x4 fah[2], fal[2], fbh[4], fbl[4];
        #pragma unroll
        for (int m = 0; m < 2; ++m) {
            fah[m] = *(const i32x4*)&As_h[wv * 32 + m * 16 + fr][fko];
            fal[m] = *(const i32x4*)&As_l[wv * 32 + m * 16 + fr][fko];
        }
        #pragma unroll
        for (int n = 0; n < 4; ++n) {
            fbh[n] = *(const i32x4*)&Bs_h[n * 16 + fr][fko];
            fbl[n] = *(const i32x4*)&Bs_l[n * 16 + fr][fko];
        }
        #pragma unroll
        for (int m = 0; m < 2; ++m)
            #pragma unroll
            for (int n = 0; n < 4; ++n) {
                acc_hh[m][n] = __builtin_amdgcn_mfma_i32_16x16x64_i8(fah[m], fbh[n], acc_hh[m][n], 0, 0, 0);
                acc_mm[m][n] = __builtin_amdgcn_mfma_i32_16x16x64_i8(fah[m], fbl[n], acc_mm[m][n], 0, 0, 0);
                acc_mm[m][n] = __builtin_amdgcn_mfma_i32_16x16x64_i8(fal[m], fbh[n], acc_mm[m][n], 0, 0, 0);
                acc_ll[m][n] = __builtin_amdgcn_mfma_i32_16x16x64_i8(fal[m], fbl[n], acc_ll[m][n], 0, 0, 0);
            }
    }

    float bv[4], wv_[4];
    #pragma unroll
    for (int n = 0; n < 4; ++n) {
        const int c = col0 + n * 16 + fr;
        bv[n] = BIAS ? bias[c] : 0.f;
        wv_[n] = wsc[c];
    }
    const int rbase = row0 + wv * 32 + (lane >> 4) * 4;
    #pragma unroll
    for (int m = 0; m < 2; ++m) {
        #pragma unroll
        for (int j = 0; j < 4; ++j) {
            const int r = rbase + m * 16 + j;
            if (r >= M) continue;
            const float qr = qsr[r];
            float ds = 1.f;
            if constexpr (OUTM == 1) ds = dscale[r];
            #pragma unroll
            for (int n = 0; n < 4; ++n) {
                const int c = col0 + n * 16 + fr;
                float dot = 65536.f * (float)acc_hh[m][n][j] + 256.f * (float)acc_mm[m][n][j]
                          + (float)acc_ll[m][n][j];
                float o = dot * qr * wv_[n] + bv[n];
                if constexpr (RELU) o = fmaxf(o, 0.f);
                if constexpr (OUTM == 1) {
                    ((float*)Cv)[(size_t)r * Nc + c] = o * ds;
                } else {
                    unsigned short h = f2bf(o);
                    unsigned short l = f2bf(o - bf2f(h));
                    unsigned short* C2 = (unsigned short*)Cv + (size_t)r * 2 * Nc + c;
                    C2[0] = h;
                    C2[Nc] = l;
                }
            }
        }
    }
}

// ---------------- bf16x3 MFMA GEMM (proven; L1, L2, W3) ----------------

template<bool RELU, bool BIAS, int OUTM>
__global__ __launch_bounds__(256) void k_gemm3(const unsigned short* __restrict__ Ahl,
        const unsigned short* __restrict__ Bth, const unsigned short* __restrict__ Btl,
        const float* __restrict__ bias, const float* __restrict__ dscale,
        void* __restrict__ Cv, int M, int K, int Nc, int ncb) {
    constexpr int PAD = 66;
    __shared__ unsigned short As_h[128][PAD];
    __shared__ unsigned short As_l[128][PAD];
    __shared__ unsigned short Bs_h[64][PAD];
    __shared__ unsigned short Bs_l[64][PAD];

    const int nwg = gridDim.x;
    const int b = blockIdx.x;
    const int q8 = nwg >> 3, r8 = nwg & 7;
    const int xcd = b & 7;
    const int swz = (xcd < r8 ? xcd * (q8 + 1) : r8 * (q8 + 1) + (xcd - r8) * q8) + (b >> 3);
    const int row0 = (swz / ncb) * 128;
    const int col0 = (swz % ncb) * 64;

    const int tid = threadIdx.x;
    const int lane = tid & 63;
    const int wv = tid >> 6;

    f32x4 acc[2][4];
    #pragma unroll
    for (int m = 0; m < 2; ++m)
        #pragma unroll
        for (int n = 0; n < 4; ++n) acc[m][n] = (f32x4)(0.f);

    const int srow = tid >> 1;
    const int skh = (tid & 1) * 32;
    int arow = row0 + srow;
    if (arow >= M) arow = M - 1;
    const unsigned short* aph = Ahl + (size_t)arow * 2 * K + skh;
    const unsigned short* apl = aph + K;

    const int bn = tid >> 2;
    const int bko = (tid & 3) * 16;
    const unsigned short* bph = Bth + (size_t)(col0 + bn) * K + bko;
    const unsigned short* bpl = Btl + (size_t)(col0 + bn) * K + bko;

    const int fr = lane & 15;
    const int fk = (lane >> 4) * 8;

    const int nk = K >> 6;
    for (int kt = 0; kt < nk; ++kt) {
        uint4 ah0 = *(const uint4*)(aph + kt * 64);
        uint4 ah1 = *(const uint4*)(aph + kt * 64 + 8);
        uint4 ah2 = *(const uint4*)(aph + kt * 64 + 16);
        uint4 ah3 = *(const uint4*)(aph + kt * 64 + 24);
        uint4 al0 = *(const uint4*)(apl + kt * 64);
        uint4 al1 = *(const uint4*)(apl + kt * 64 + 8);
        uint4 al2 = *(const uint4*)(apl + kt * 64 + 16);
        uint4 al3 = *(const uint4*)(apl + kt * 64 + 24);
        uint4 bh0 = *(const uint4*)(bph + kt * 64);
        uint4 bh1 = *(const uint4*)(bph + kt * 64 + 8);
        uint4 bl0 = *(const uint4*)(bpl + kt * 64);
        uint4 bl1 = *(const uint4*)(bpl + kt * 64 + 8);

        __syncthreads();

        *(uint4*)&As_h[srow][skh] = ah0;
        *(uint4*)&As_h[srow][skh + 8] = ah1;
        *(uint4*)&As_h[srow][skh + 16] = ah2;
        *(uint4*)&As_h[srow][skh + 24] = ah3;
        *(uint4*)&As_l[srow][skh] = al0;
        *(uint4*)&As_l[srow][skh + 8] = al1;
        *(uint4*)&As_l[srow][skh + 16] = al2;
        *(uint4*)&As_l[srow][skh + 24] = al3;
        *(uint4*)&Bs_h[bn][bko] = bh0;
        *(uint4*)&Bs_h[bn][bko + 8] = bh1;
        *(uint4*)&Bs_l[bn][bko] = bl0;
        *(uint4*)&Bs_l[bn][bko + 8] = bl1;

        __syncthreads();

        #pragma unroll
        for (int ks = 0; ks < 2; ++ks) {
            const int ko = ks * 32 + fk;
            bf16x8 ah[2], al[2], bh[4], bl[4];
            #pragma unroll
            for (int m = 0; m < 2; ++m) {
                ah[m] = *(const bf16x8*)&As_h[wv * 32 + m * 16 + fr][ko];
                al[m] = *(const bf16x8*)&As_l[wv * 32 + m * 16 + fr][ko];
            }
            #pragma unroll
            for (int n = 0; n < 4; ++n) {
                bh[n] = *(const bf16x8*)&Bs_h[n * 16 + fr][ko];
                bl[n] = *(const bf16x8*)&Bs_l[n * 16 + fr][ko];
            }
            #pragma unroll
            for (int m = 0; m < 2; ++m)
                #pragma unroll
                for (int n = 0; n < 4; ++n) {
                    acc[m][n] = __builtin_amdgcn_mfma_f32_16x16x32_bf16(ah[m], bh[n], acc[m][n], 0, 0, 0);
                    acc[m][n] = __builtin_amdgcn_mfma_f32_16x16x32_bf16(ah[m], bl[n], acc[m][n], 0, 0, 0);
                    acc[m][n] = __builtin_amdgcn_mfma_f32_16x16x32_bf16(al[m], bh[n], acc[m][n], 0, 0, 0);
                }
        }
    }

    float bv[4];
    #pragma unroll
    for (int n = 0; n < 4; ++n) bv[n] = BIAS ? bias[col0 + n * 16 + fr] : 0.f;
    const int rbase = row0 + wv * 32 + (lane >> 4) * 4;
    #pragma unroll
    for (int m = 0; m < 2; ++m) {
        #pragma unroll
        for (int j = 0; j < 4; ++j) {
            const int r = rbase + m * 16 + j;
            if (r >= M) continue;
            float ds = 1.f;
            if constexpr (OUTM == 1) ds = dscale[r];
            #pragma unroll
            for (int n = 0; n < 4; ++n) {
                const int c = col0 + n * 16 + fr;
                float o = acc[m][n][j] + bv[n];
                if constexpr (RELU) o = fmaxf(o, 0.f);
                if constexpr (OUTM == 1) {
                    ((float*)Cv)[(size_t)r * Nc + c] = o * ds;
                } else {
                    unsigned short h = f2bf(o);
                    unsigned short l = f2bf(o - bf2f(h));
                    unsigned short* C2 = (unsigned short*)Cv + (size_t)r * 2 * Nc + c;
                    C2[0] = h;
                    C2[Nc] = l;
                }
            }
        }
    }
}

// ---------------- conditional softmax over 64 classes ----------------

__global__ __launch_bounds__(256) void k_softmax(float* __restrict__ out, const int* __restrict__ mode, int n) {
    if (*mode == 1) return;
    int lane = threadIdx.x & 63;
    int i = blockIdx.x * 4 + (threadIdx.x >> 6);
    if (i >= n) return;
    float v = out[(size_t)i * 64 + lane];
    float m = v;
    #pragma unroll
    for (int off = 32; off > 0; off >>= 1) m = fmaxf(m, __shfl_xor(m, off));
    float e = __expf(v - m);
    float s = e;
    #pragma unroll
    for (int off = 32; off > 0; off >>= 1) s += __shfl_xor(s, off);
    out[(size_t)i * 64 + lane] = e / s;
}

// ---------------- launch ----------------

extern "C" void kernel_launch(void* const* d_in, const int* in_sizes, int n_in,
                              void* d_out, int out_size, void* d_ws, size_t ws_size,
                              hipStream_t stream) {
    const float* x   = (const float*)d_in[0];
    const float* W1  = (const float*)d_in[1];
    const float* b1  = (const float*)d_in[2];
    const float* W2  = (const float*)d_in[3];
    const float* b2  = (const float*)d_in[4];
    const float* L1w = (const float*)d_in[5];
    const float* L1b = (const float*)d_in[6];
    const float* L2w = (const float*)d_in[7];
    const float* L2b = (const float*)d_in[8];
    const float* W3  = (const float*)d_in[9];
    const float* b3  = (const float*)d_in[10];
    const int* adj   = (const int*)d_in[11];
    const int* adj2  = (const int*)d_in[12];
    const int* mode  = (const int*)d_in[13];
    float* out = (float*)d_out;

    char* ws = (char*)d_ws;
    auto alloc = [&](size_t bytes) {
        char* p = ws;
        ws += (bytes + 255) & ~(size_t)255;
        return p;
    };
    char*  bufA  = alloc((size_t)NNODES * 256 * 4);   // 51.2 MB
    char*  bufB  = alloc((size_t)NNODES * 256 * 4);   // 51.2 MB
    int*   rp1   = (int*)alloc((NNODES + 1) * 4);
    int*   col1  = (int*)alloc((size_t)NEDGES * 4);
    int*   rp2   = (int*)alloc((NNODES + 1) * 4);
    int*   col2  = (int*)alloc((size_t)NEDGES * 4);
    float* dinv1 = (float*)alloc(NNODES * 4);
    float* dinv2 = (float*)alloc(NNODES * 4);
    int*   bcnt  = (int*)alloc(2 * NBKT * 4);
    int*   bbase = (int*)alloc(2 * NBKT * 4);
    float* qsA   = (float*)alloc(NNODES * 4);
    float* qsB   = (float*)alloc(NNODES * 4);
    // i8 weights (W1, W2) + per-col scales
    signed char* B1h = (signed char*)alloc(256 * D_IN);
    signed char* B1l = (signed char*)alloc(256 * D_IN);
    signed char* B2h = (signed char*)alloc(256 * D_H);
    signed char* B2l = (signed char*)alloc(256 * D_H);
    float* ws1 = (float*)alloc(256 * 4);
    float* ws2 = (float*)alloc(256 * 4);
    // bf16 hi/lo weights (L1w, L2w, W3)
    unsigned short* L1h = (unsigned short*)alloc(D_H * D_IN * 2);
    unsigned short* L1l = (unsigned short*)alloc(D_H * D_IN * 2);
    unsigned short* L2h = (unsigned short*)alloc(D_IN * D_H * 2);
    unsigned short* L2l = (unsigned short*)alloc(D_IN * D_H * 2);
    unsigned short* W3h = (unsigned short*)alloc(D_H * D_OUT * 2);
    unsigned short* W3l = (unsigned short*)alloc(D_H * D_OUT * 2);
    // binned edge arrays alias bufA (consumed before bufA's first write)
    unsigned* binned = (unsigned*)bufA;

    const int AGB = (NNODES + 3) / 4;
    const int MT = (NNODES + 127) / 128;
    const int BINB = (NEDGES + CHUNK - 1) / CHUNK;    // 391

    // weight preconversion
    k_wconv_all<<<(81920 + 255) / 256, 256, 0, stream>>>(L1w, L2w, W3,
        L1h, L1l, L2h, L2l, W3h, W3l);
    k_wconv_i8<<<128, 256, 0, stream>>>(W1, W2, B1h, B1l, B2h, B2l, ws1, ws2);

    // CSR build
    hipMemsetAsync(bcnt, 0, 2 * NBKT * 4, stream);
    k_bin<<<dim3(BINB, 2), 256, 0, stream>>>(adj, adj2, bcnt, binned, NEDGES);
    k_bktscan<<<1, 256, 0, stream>>>(bcnt, bbase, rp1, rp2);
    k_csr_bucket<<<dim3(NBKT, 2), 256, 0, stream>>>(binned, bcnt, bbase, rp1, rp2,
                                                    dinv1, dinv2, col1, col2, NNODES);

    // q(x .* dinv1) -> bufA int16 + qsA
    k_quant<128, true><<<AGB, 256, 0, stream>>>(x, dinv1, (short*)bufA, qsA, NNODES);
    // conv1 agg: bufA(q128, qsA) -> bufB i8 planes + qsB
    k_agg3<128, 0><<<AGB, 256, 0, stream>>>((const short*)bufA, qsA, rp1, col1, dinv1, nullptr, bufB, qsB, NNODES);
    // conv1 gemm (i8): relu((.)W1+b1) * dinv2 -> bufA (f32,256)
    k_gemm_i8<true, true, 1><<<MT * 4, 256, 0, stream>>>(
        (const unsigned char*)bufB, qsB, B1h, B1l, ws1, b1, dinv2, bufA, NNODES, D_IN, D_H, 4);
    // quantize: bufA(f32,256) -> bufB int16 + qsA
    k_quant<256, false><<<AGB, 256, 0, stream>>>((const float*)bufA, nullptr, (short*)bufB, qsA, NNODES);
    // conv2 agg: bufB(q256, qsA) -> bufA i8 planes + qsB
    k_agg3<256, 0><<<AGB, 256, 0, stream>>>((const short*)bufB, qsA, rp2, col2, dinv2, nullptr, bufA, qsB, NNODES);
    // conv2 gemm (i8): relu((.)W2+b2) -> bufB (hl,256)
    k_gemm_i8<true, true, 2><<<MT * 4, 256, 0, stream>>>(
        (const unsigned char*)bufA, qsB, B2h, B2l, ws2, b2, nullptr, bufB, NNODES, D_H, D_H, 4);
    // L1: relu((.)L1w+b) -> bufA (hl,128)
    k_gemm3<true, true, 2><<<MT * 2, 256, 0, stream>>>(
        (const unsigned short*)bufB, L1h, L1l, L1b, nullptr, bufA, NNODES, D_H, D_IN, 2);
    // L2: relu((.)L2w+b) -> bufB (hl,256)
    k_gemm3<true, true, 2><<<MT * 4, 256, 0, stream>>>(
        (const unsigned short*)bufA, L2h, L2l, L2b, nullptr, bufB, NNODES, D_IN, D_H, 4);
    // conv3 gemm: ((.)W3) * dinv2 -> bufA (f32,64)
    k_gemm3<false, false, 1><<<MT * 1, 256, 0, stream>>>(
        (const unsigned short*)bufB, W3h, W3l, nullptr, dinv2, bufA, NNODES, D_H, D_OUT, 1);
    // quantize: bufA(f32,64) -> bufB q64 + qsA
    k_quant<64, false><<<AGB, 256, 0, stream>>>((const float*)bufA, nullptr, (short*)bufB, qsA, NNODES);
    // conv3 agg: bufB(q64, qsA) -> out (f32 + b3)
    k_agg3<64, 1><<<AGB, 256, 0, stream>>>((const short*)bufB, qsA, rp2, col2, dinv2, b3, out, nullptr, NNODES);
    // optional softmax (mode != 1)
    k_softmax<<<AGB, 256, 0, stream>>>(out, mode, NNODES);
}

// Round 12
// 326.318 us; speedup vs baseline: 1.0842x; 1.0842x over previous
//
#include <hip/hip_runtime.h>
#include <hip/hip_bf16.h>
#include <cstdint>
#include <cstddef>

#define NNODES 50000
#define NEDGES 800000
#define D_IN   128
#define D_H    256
#define D_OUT  64
#define BSH    9
#define BKN    (1 << BSH)                             // 512 nodes per bucket
#define NBKT   ((NNODES + BKN - 1) / BKN)             // 98
#define MAXB   12288                                  // cap per bucket (45 sigma)
#define CHUNK  2048
#define QMAX   32639.0f                               // 127*256+127: i8-splittable int16 range

typedef __attribute__((ext_vector_type(8))) short bf16x8;
typedef __attribute__((ext_vector_type(4))) float f32x4;
typedef __attribute__((ext_vector_type(4))) int   i32x4;

__device__ __forceinline__ unsigned short f2bf(float f) {
    unsigned u = __builtin_bit_cast(unsigned, f);
    unsigned r = (u + 0x7FFFu + ((u >> 16) & 1u)) >> 16;
    return (unsigned short)r;
}
__device__ __forceinline__ float bf2f(unsigned short h) {
    unsigned u = ((unsigned)h) << 16;
    return __builtin_bit_cast(float, u);
}

// ---------------- CSR build: bin -> bucket scan -> fused per-bucket CSR ----------------

__global__ __launch_bounds__(256) void k_bin(const int* __restrict__ adjA, const int* __restrict__ adjB,
                                             int* __restrict__ bcnt, unsigned* __restrict__ binned, int e) {
    __shared__ int h[NBKT], pfx[NBKT], put[NBKT], gbase[NBKT];
    __shared__ unsigned stage[CHUNK];
    const int g = blockIdx.y;
    const int* srcp = g ? adjB : adjA;
    const int* dstp = srcp + e;
    unsigned* outp = binned + (size_t)g * NBKT * MAXB;
    int* bc = bcnt + g * NBKT;
    const int tid = threadIdx.x;
    const int base = blockIdx.x * CHUNK;
    const int nrem = min(CHUNK, e - base);
    if (nrem <= 0) return;

    for (int t = tid; t < NBKT; t += 256) { h[t] = 0; put[t] = 0; }
    __syncthreads();

    unsigned pv[8];
    int bv[8];
    #pragma unroll
    for (int q = 0; q < 8; ++q) {
        int i = base + q * 256 + tid;
        bv[q] = -1;
        if (i < e) {
            int s = srcp[i];
            int d = dstp[i];
            pv[q] = ((unsigned)d << 16) | (unsigned)s;
            bv[q] = d >> BSH;
            atomicAdd(&h[bv[q]], 1);
        }
    }
    __syncthreads();
    if (tid == 0) {
        int r = 0;
        for (int k = 0; k < NBKT; ++k) { pfx[k] = r; r += h[k]; }
    }
    __syncthreads();
    #pragma unroll
    for (int q = 0; q < 8; ++q) {
        if (bv[q] >= 0) {
            int p = pfx[bv[q]] + atomicAdd(&put[bv[q]], 1);
            stage[p] = pv[q];
        }
    }
    __syncthreads();
    if (tid < NBKT && h[tid] > 0) gbase[tid] = atomicAdd(&bc[tid], h[tid]);
    __syncthreads();
    for (int idx = tid; idx < nrem; idx += 256) {
        unsigned v = stage[idx];
        int bb = v >> (16 + BSH);
        outp[(size_t)bb * MAXB + gbase[bb] + (idx - pfx[bb])] = v;
    }
}

__global__ void k_bktscan(const int* __restrict__ bcnt, int* __restrict__ bbase,
                          int* __restrict__ rp1, int* __restrict__ rp2) {
    __shared__ int s[2][NBKT];
    int t = threadIdx.x;
    if (t < NBKT) s[0][t] = bcnt[t];
    else if (t < 2 * NBKT) s[1][t - NBKT] = bcnt[t];
    __syncthreads();
    if (t < 2) {
        int r = 0;
        for (int k = 0; k < NBKT; ++k) { int v = s[t][k]; s[t][k] = r; r += v; }
    }
    __syncthreads();
    if (t < NBKT) bbase[t] = s[0][t];
    else if (t < 2 * NBKT) bbase[t] = s[1][t - NBKT];
    if (t == 0) { rp1[NNODES] = NEDGES; rp2[NNODES] = NEDGES; }
}

__global__ __launch_bounds__(256) void k_csr_bucket(const unsigned* __restrict__ binned,
                                                    const int* __restrict__ bcnt, const int* __restrict__ bbase,
                                                    int* __restrict__ rp1, int* __restrict__ rp2,
                                                    float* __restrict__ dinv1, float* __restrict__ dinv2,
                                                    int* __restrict__ col1, int* __restrict__ col2, int n) {
    __shared__ int lc[BKN];
    __shared__ int loff[BKN];
    __shared__ int ps[256];
    __shared__ int srt[MAXB];
    const int g = blockIdx.y;
    const int b = blockIdx.x;
    const unsigned* in = binned + (size_t)g * NBKT * MAXB + (size_t)b * MAXB;
    int* rp = g ? rp2 : rp1;
    float* dinv = g ? dinv2 : dinv1;
    int* col = g ? col2 : col1;
    const int nb = bcnt[g * NBKT + b];
    const int base0 = bbase[g * NBKT + b];
    const int nodebase = b << BSH;
    const int tid = threadIdx.x;

    for (int t = tid; t < BKN; t += 256) lc[t] = 0;
    __syncthreads();
    for (int t = tid; t < nb; t += 256)
        atomicAdd(&lc[(in[t] >> 16) & (BKN - 1)], 1);
    __syncthreads();
    int c0 = lc[2 * tid], c1 = lc[2 * tid + 1];
    int pair = c0 + c1;
    int sum = pair;
    ps[tid] = pair;
    __syncthreads();
    #pragma unroll
    for (int off = 1; off < 256; off <<= 1) {
        int u = (tid >= off) ? ps[tid - off] : 0;
        __syncthreads();
        sum += u;
        ps[tid] = sum;
        __syncthreads();
    }
    int excl = sum - pair;
    loff[2 * tid] = excl;
    loff[2 * tid + 1] = excl + c0;
    __syncthreads();
    for (int t = tid; t < BKN; t += 256) {
        int node = nodebase + t;
        if (node < n) {
            rp[node] = base0 + loff[t];
            dinv[node] = rsqrtf((float)(lc[t] + 1));
        }
    }
    __syncthreads();
    for (int t = tid; t < nb; t += 256) {
        unsigned v = in[t];
        int pos = atomicAdd(&loff[(v >> 16) & (BKN - 1)], 1);
        srt[pos] = (int)(v & 0xFFFFu);
    }
    __syncthreads();
    for (int t = tid; t < nb; t += 256) col[base0 + t] = srt[t];
}

// ---------------- quantize: fp32 rows -> int16 rows + per-row scale ----------------

template<int F, bool PRESCALE>
__global__ __launch_bounds__(256) void k_quant(const float* __restrict__ in, const float* __restrict__ dscale,
                                               short* __restrict__ q, float* __restrict__ qs, int n) {
    constexpr int VPT = F / 64;
    const int lane = threadIdx.x & 63;
    const int i = blockIdx.x * 4 + (threadIdx.x >> 6);
    if (i >= n) return;
    float v[VPT];
    const float* p = in + (size_t)i * F + lane * VPT;
    if constexpr (VPT == 4) { float4 t = *(const float4*)p; v[0] = t.x; v[1] = t.y; v[2] = t.z; v[3] = t.w; }
    else if constexpr (VPT == 2) { float2 t = *(const float2*)p; v[0] = t.x; v[1] = t.y; }
    else v[0] = *p;
    if constexpr (PRESCALE) {
        float d = dscale[i];
        #pragma unroll
        for (int c = 0; c < VPT; ++c) v[c] *= d;
    }
    float m = 0.f;
    #pragma unroll
    for (int c = 0; c < VPT; ++c) m = fmaxf(m, fabsf(v[c]));
    #pragma unroll
    for (int off = 32; off > 0; off >>= 1) m = fmaxf(m, __shfl_xor(m, off));
    float inv = (m > 0.f) ? 32767.0f / m : 0.f;
    short* qp = q + (size_t)i * F + lane * VPT;
    if constexpr (VPT == 4) {
        short4 o;
        o.x = (short)__float2int_rn(v[0] * inv);
        o.y = (short)__float2int_rn(v[1] * inv);
        o.z = (short)__float2int_rn(v[2] * inv);
        o.w = (short)__float2int_rn(v[3] * inv);
        *(short4*)qp = o;
    } else if constexpr (VPT == 2) {
        short2 o;
        o.x = (short)__float2int_rn(v[0] * inv);
        o.y = (short)__float2int_rn(v[1] * inv);
        *(short2*)qp = o;
    } else {
        *qp = (short)__float2int_rn(v[0] * inv);
    }
    if (lane == 0) qs[i] = m * (1.0f / 32767.0f);
}

// ---------------- Aggregation over int16-quantized prescaled input ----------------
// OUTM 0: emit per-row-quantized i8 hi/lo planes (A8h | A8l, each [n][F]) + qs_out
// OUTM 1: fp32 + bias (final output)
// 8-wide edge unroll: 8 gathers in flight (latency hiding).

template<int F, int OUTM>
__global__ __launch_bounds__(256) void k_agg3(const short* __restrict__ q, const float* __restrict__ qs,
                                              const int* __restrict__ rp, const int* __restrict__ col,
                                              const float* __restrict__ dinv, const float* __restrict__ bias,
                                              void* __restrict__ outv, float* __restrict__ qs_out, int n) {
    constexpr int VPT = F / 64;
    const int lane = threadIdx.x & 63;
    const int i = blockIdx.x * 4 + (threadIdx.x >> 6);
    if (i >= n) return;
    const short* ql = q + lane * VPT;
    float acc[VPT];
    #pragma unroll
    for (int c = 0; c < VPT; ++c) acc[c] = 0.f;

    int k = rp[i], end = rp[i + 1];

    auto body1 = [&](int j) {
        float s = qs[j];
        const short* pj = ql + (size_t)j * F;
        if constexpr (VPT == 4) {
            short4 v = *(const short4*)pj;
            acc[0] += s * (float)v.x; acc[1] += s * (float)v.y;
            acc[2] += s * (float)v.z; acc[3] += s * (float)v.w;
        } else if constexpr (VPT == 2) {
            short2 v = *(const short2*)pj;
            acc[0] += s * (float)v.x; acc[1] += s * (float)v.y;
        } else {
            acc[0] += s * (float)(*pj);
        }
    };

    body1(i);  // self loop
    if constexpr (VPT == 4) {
        for (; k + 8 <= end; k += 8) {
            int j[8]; float s[8]; short4 v[8];
            #pragma unroll
            for (int u = 0; u < 8; ++u) j[u] = col[k + u];
            #pragma unroll
            for (int u = 0; u < 8; ++u) s[u] = qs[j[u]];
            #pragma unroll
            for (int u = 0; u < 8; ++u) v[u] = *(const short4*)(ql + (size_t)j[u] * F);
            #pragma unroll
            for (int u = 0; u < 8; ++u) {
                acc[0] += s[u] * (float)v[u].x; acc[1] += s[u] * (float)v[u].y;
                acc[2] += s[u] * (float)v[u].z; acc[3] += s[u] * (float)v[u].w;
            }
        }
    } else if constexpr (VPT == 2) {
        for (; k + 8 <= end; k += 8) {
            int j[8]; float s[8]; short2 v[8];
            #pragma unroll
            for (int u = 0; u < 8; ++u) j[u] = col[k + u];
            #pragma unroll
            for (int u = 0; u < 8; ++u) s[u] = qs[j[u]];
            #pragma unroll
            for (int u = 0; u < 8; ++u) v[u] = *(const short2*)(ql + (size_t)j[u] * F);
            #pragma unroll
            for (int u = 0; u < 8; ++u) {
                acc[0] += s[u] * (float)v[u].x; acc[1] += s[u] * (float)v[u].y;
            }
        }
    }
    for (; k + 4 <= end; k += 4) {
        int j0 = col[k], j1 = col[k + 1], j2 = col[k + 2], j3 = col[k + 3];
        float s0 = qs[j0], s1 = qs[j1], s2 = qs[j2], s3 = qs[j3];
        if constexpr (VPT == 4) {
            short4 v0 = *(const short4*)(ql + (size_t)j0 * F);
            short4 v1 = *(const short4*)(ql + (size_t)j1 * F);
            short4 v2 = *(const short4*)(ql + (size_t)j2 * F);
            short4 v3 = *(const short4*)(ql + (size_t)j3 * F);
            acc[0] += s0 * (float)v0.x + s1 * (float)v1.x + s2 * (float)v2.x + s3 * (float)v3.x;
            acc[1] += s0 * (float)v0.y + s1 * (float)v1.y + s2 * (float)v2.y + s3 * (float)v3.y;
            acc[2] += s0 * (float)v0.z + s1 * (float)v1.z + s2 * (float)v2.z + s3 * (float)v3.z;
            acc[3] += s0 * (float)v0.w + s1 * (float)v1.w + s2 * (float)v2.w + s3 * (float)v3.w;
        } else if constexpr (VPT == 2) {
            short2 v0 = *(const short2*)(ql + (size_t)j0 * F);
            short2 v1 = *(const short2*)(ql + (size_t)j1 * F);
            short2 v2 = *(const short2*)(ql + (size_t)j2 * F);
            short2 v3 = *(const short2*)(ql + (size_t)j3 * F);
            acc[0] += s0 * (float)v0.x + s1 * (float)v1.x + s2 * (float)v2.x + s3 * (float)v3.x;
            acc[1] += s0 * (float)v0.y + s1 * (float)v1.y + s2 * (float)v2.y + s3 * (float)v3.y;
        } else {
            float v0 = (float)ql[(size_t)j0 * F];
            float v1 = (float)ql[(size_t)j1 * F];
            float v2 = (float)ql[(size_t)j2 * F];
            float v3 = (float)ql[(size_t)j3 * F];
            acc[0] += s0 * v0 + s1 * v1 + s2 * v2 + s3 * v3;
        }
    }
    for (; k < end; ++k) body1(col[k]);

    float di = dinv[i];
    if constexpr (OUTM == 0) {
        float vals[VPT];
        float m = 0.f;
        #pragma unroll
        for (int c = 0; c < VPT; ++c) { vals[c] = acc[c] * di; m = fmaxf(m, fabsf(vals[c])); }
        #pragma unroll
        for (int off = 32; off > 0; off >>= 1) m = fmaxf(m, __shfl_xor(m, off));
        float inv = (m > 0.f) ? QMAX / m : 0.f;
        unsigned ph = 0, pl = 0;
        #pragma unroll
        for (int c = 0; c < VPT; ++c) {
            int qv = __float2int_rn(vals[c] * inv);
            int ah = (qv + 128) >> 8;
            int al = qv - (ah << 8);
            ph |= (unsigned)(ah & 0xFF) << (8 * c);
            pl |= (unsigned)(al & 0xFF) << (8 * c);
        }
        unsigned char* o8h = (unsigned char*)outv;
        unsigned char* o8l = o8h + (size_t)n * F;
        if constexpr (VPT == 4) {
            *(unsigned*)(o8h + (size_t)i * F + lane * 4) = ph;
            *(unsigned*)(o8l + (size_t)i * F + lane * 4) = pl;
        } else if constexpr (VPT == 2) {
            *(unsigned short*)(o8h + (size_t)i * F + lane * 2) = (unsigned short)ph;
            *(unsigned short*)(o8l + (size_t)i * F + lane * 2) = (unsigned short)pl;
        } else {
            o8h[(size_t)i * F + lane] = (unsigned char)ph;
            o8l[(size_t)i * F + lane] = (unsigned char)pl;
        }
        if (lane == 0) qs_out[i] = m * (1.0f / QMAX);
    } else {
        float* o = (float*)outv + (size_t)i * F + lane * VPT;
        #pragma unroll
        for (int c = 0; c < VPT; ++c) o[c] = acc[c] * di + bias[lane * VPT + c];
    }
}

// ---------------- weight preconvert: bf16 hi/lo path (L1w, L2w, W3) ----------------

__device__ __forceinline__ void wconv1(const float* __restrict__ W, unsigned short* __restrict__ Th,
                                       unsigned short* __restrict__ Tl, int idx, int K, int Nc) {
    int k = idx / Nc, n = idx - k * Nc;
    float v = W[idx];
    unsigned short h = f2bf(v);
    unsigned short l = f2bf(v - bf2f(h));
    Th[(size_t)n * K + k] = h;
    Tl[(size_t)n * K + k] = l;
}

__global__ void k_wconv_all(const float* L1w, const float* L2w, const float* W3,
                            unsigned short* L1h, unsigned short* L1l, unsigned short* L2h, unsigned short* L2l,
                            unsigned short* W3h, unsigned short* W3l) {
    int idx = blockIdx.x * blockDim.x + threadIdx.x;
    if (idx < 32768)        wconv1(L1w, L1h, L1l, idx, D_H, D_IN);
    else if (idx < 65536)   wconv1(L2w, L2h, L2l, idx - 32768, D_IN, D_H);
    else if (idx < 81920)   wconv1(W3, W3h, W3l, idx - 65536, D_H, D_OUT);
}

// ---------------- weight preconvert: int16 per-col scale -> i8 hi/lo planes (W1, W2) ----------------

__global__ __launch_bounds__(256) void k_wconv_i8(const float* __restrict__ W1, const float* __restrict__ W2,
        signed char* __restrict__ B1h, signed char* __restrict__ B1l,
        signed char* __restrict__ B2h, signed char* __restrict__ B2l,
        float* __restrict__ ws1, float* __restrict__ ws2) {
    const int c4 = blockIdx.x * 4 + (threadIdx.x >> 6);
    const int lane = threadIdx.x & 63;
    const float* W; signed char *Bh, *Bl; float* ws; int K, c;
    if (c4 < 256) { W = W1; Bh = B1h; Bl = B1l; ws = ws1; K = D_IN; c = c4; }
    else          { W = W2; Bh = B2h; Bl = B2l; ws = ws2; K = D_H;  c = c4 - 256; }
    float m = 0.f;
    for (int k = lane; k < K; k += 64) m = fmaxf(m, fabsf(W[(size_t)k * D_H + c]));
    #pragma unroll
    for (int off = 32; off > 0; off >>= 1) m = fmaxf(m, __shfl_xor(m, off));
    float inv = (m > 0.f) ? QMAX / m : 0.f;
    for (int k = lane; k < K; k += 64) {
        int qv = __float2int_rn(W[(size_t)k * D_H + c] * inv);
        int ah = (qv + 128) >> 8;
        int al = qv - (ah << 8);
        Bh[(size_t)c * K + k] = (signed char)ah;
        Bl[(size_t)c * K + k] = (signed char)al;
    }
    if (lane == 0) ws[c] = m * (1.0f / QMAX);
}

// ---------------- i8 split MFMA GEMM (hh + cross terms; ll dropped: ~1.6e-5 rel) ----------------

template<bool RELU, bool BIAS, int OUTM>
__global__ __launch_bounds__(256) void k_gemm_i8(const unsigned char* __restrict__ A8,
        const float* __restrict__ qsr,
        const signed char* __restrict__ B8h, const signed char* __restrict__ B8l,
        const float* __restrict__ wsc,
        const float* __restrict__ bias, const float* __restrict__ dscale,
        void* __restrict__ Cv, int M, int K, int Nc, int ncb) {
    constexpr int PADB = 68;
    __shared__ unsigned char As_h[128][PADB];
    __shared__ unsigned char As_l[128][PADB];
    __shared__ unsigned char Bs_h[64][PADB];
    __shared__ unsigned char Bs_l[64][PADB];

    const int nwg = gridDim.x;
    const int b = blockIdx.x;
    const int q8 = nwg >> 3, r8 = nwg & 7;
    const int xcd = b & 7;
    const int swz = (xcd < r8 ? xcd * (q8 + 1) : r8 * (q8 + 1) + (xcd - r8) * q8) + (b >> 3);
    const int row0 = (swz / ncb) * 128;
    const int col0 = (swz % ncb) * 64;

    const int tid = threadIdx.x;
    const int lane = tid & 63;
    const int wv = tid >> 6;

    i32x4 acc_hh[2][4], acc_mm[2][4];
    #pragma unroll
    for (int m = 0; m < 2; ++m)
        #pragma unroll
        for (int n = 0; n < 4; ++n) {
            acc_hh[m][n] = (i32x4)(0);
            acc_mm[m][n] = (i32x4)(0);
        }

    const int srow = tid >> 1;
    const int skh = (tid & 1) * 32;
    int arow = row0 + srow;
    if (arow >= M) arow = M - 1;
    const unsigned char* aph = A8 + (size_t)arow * K + skh;
    const unsigned char* apl = aph + (size_t)M * K;

    const int bn = tid >> 2;
    const int bko = (tid & 3) * 16;
    const signed char* bph = B8h + (size_t)(col0 + bn) * K + bko;
    const signed char* bpl = B8l + (size_t)(col0 + bn) * K + bko;

    const int fr = lane & 15;
    const int fko = (lane >> 4) * 16;

    const int nk = K >> 6;
    for (int kt = 0; kt < nk; ++kt) {
        uint4 ah0 = *(const uint4*)(aph + kt * 64);
        uint4 ah1 = *(const uint4*)(aph + kt * 64 + 16);
        uint4 al0 = *(const uint4*)(apl + kt * 64);
        uint4 al1 = *(const uint4*)(apl + kt * 64 + 16);
        uint4 bh0 = *(const uint4*)(bph + kt * 64);
        uint4 bl0 = *(const uint4*)(bpl + kt * 64);

        __syncthreads();

        *(uint4*)&As_h[srow][skh] = ah0;
        *(uint4*)&As_h[srow][skh + 16] = ah1;
        *(uint4*)&As_l[srow][skh] = al0;
        *(uint4*)&As_l[srow][skh + 16] = al1;
        *(uint4*)&Bs_h[bn][bko] = bh0;
        *(uint4*)&Bs_l[bn][bko] = bl0;

        __syncthreads();

        i32x4 fah[2], fal[2], fbh[4], fbl[4];
        #pragma unroll
        for (int m = 0; m < 2; ++m) {
            fah[m] = *(const i32x4*)&As_h[wv * 32 + m * 16 + fr][fko];
            fal[m] = *(const i32x4*)&As_l[wv * 32 + m * 16 + fr][fko];
        }
        #pragma unroll
        for (int n = 0; n < 4; ++n) {
            fbh[n] = *(const i32x4*)&Bs_h[n * 16 + fr][fko];
            fbl[n] = *(const i32x4*)&Bs_l[n * 16 + fr][fko];
        }
        #pragma unroll
        for (int m = 0; m < 2; ++m)
            #pragma unroll
            for (int n = 0; n < 4; ++n) {
                acc_hh[m][n] = __builtin_amdgcn_mfma_i32_16x16x64_i8(fah[m], fbh[n], acc_hh[m][n], 0, 0, 0);
                acc_mm[m][n] = __builtin_amdgcn_mfma_i32_16x16x64_i8(fah[m], fbl[n], acc_mm[m][n], 0, 0, 0);
                acc_mm[m][n] = __builtin_amdgcn_mfma_i32_16x16x64_i8(fal[m], fbh[n], acc_mm[m][n], 0, 0, 0);
            }
    }

    float bv[4], wv_[4];
    #pragma unroll
    for (int n = 0; n < 4; ++n) {
        const int c = col0 + n * 16 + fr;
        bv[n] = BIAS ? bias[c] : 0.f;
        wv_[n] = wsc[c];
    }
    const int rbase = row0 + wv * 32 + (lane >> 4) * 4;
    #pragma unroll
    for (int m = 0; m < 2; ++m) {
        #pragma unroll
        for (int j = 0; j < 4; ++j) {
            const int r = rbase + m * 16 + j;
            if (r >= M) continue;
            const float qr = qsr[r];
            float ds = 1.f;
            if constexpr (OUTM == 1) ds = dscale[r];
            #pragma unroll
            for (int n = 0; n < 4; ++n) {
                const int c = col0 + n * 16 + fr;
                float dot = 65536.f * (float)acc_hh[m][n][j] + 256.f * (float)acc_mm[m][n][j];
                float o = dot * qr * wv_[n] + bv[n];
                if constexpr (RELU) o = fmaxf(o, 0.f);
                if constexpr (OUTM == 1) {
                    ((float*)Cv)[(size_t)r * Nc + c] = o * ds;
                } else {
                    unsigned short h = f2bf(o);
                    unsigned short l = f2bf(o - bf2f(h));
                    unsigned short* C2 = (unsigned short*)Cv + (size_t)r * 2 * Nc + c;
                    C2[0] = h;
                    C2[Nc] = l;
                }
            }
        }
    }
}

// ---------------- bf16x3 MFMA GEMM (L1, L2, W3) ----------------
// OUTM 1: fp32 * dscale[row]; OUTM 2: bf16 hi/lo planes; OUTM 3: int16 + per-row qs
// (OUTM 3 requires ncb==1: block owns all Nc cols of its rows).

template<bool RELU, bool BIAS, int OUTM>
__global__ __launch_bounds__(256) void k_gemm3(const unsigned short* __restrict__ Ahl,
        const unsigned short* __restrict__ Bth, const unsigned short* __restrict__ Btl,
        const float* __restrict__ bias, const float* __restrict__ dscale,
        void* __restrict__ Cv, float* __restrict__ qs_out, int M, int K, int Nc, int ncb) {
    constexpr int PAD = 66;
    __shared__ unsigned short As_h[128][PAD];
    __shared__ unsigned short As_l[128][PAD];
    __shared__ unsigned short Bs_h[64][PAD];
    __shared__ unsigned short Bs_l[64][PAD];

    const int nwg = gridDim.x;
    const int b = blockIdx.x;
    const int q8 = nwg >> 3, r8 = nwg & 7;
    const int xcd = b & 7;
    const int swz = (xcd < r8 ? xcd * (q8 + 1) : r8 * (q8 + 1) + (xcd - r8) * q8) + (b >> 3);
    const int row0 = (swz / ncb) * 128;
    const int col0 = (swz % ncb) * 64;

    const int tid = threadIdx.x;
    const int lane = tid & 63;
    const int wv = tid >> 6;

    f32x4 acc[2][4];
    #pragma unroll
    for (int m = 0; m < 2; ++m)
        #pragma unroll
        for (int n = 0; n < 4; ++n) acc[m][n] = (f32x4)(0.f);

    const int srow = tid >> 1;
    const int skh = (tid & 1) * 32;
    int arow = row0 + srow;
    if (arow >= M) arow = M - 1;
    const unsigned short* aph = Ahl + (size_t)arow * 2 * K + skh;
    const unsigned short* apl = aph + K;

    const int bn = tid >> 2;
    const int bko = (tid & 3) * 16;
    const unsigned short* bph = Bth + (size_t)(col0 + bn) * K + bko;
    const unsigned short* bpl = Btl + (size_t)(col0 + bn) * K + bko;

    const int fr = lane & 15;
    const int fk = (lane >> 4) * 8;

    const int nk = K >> 6;
    for (int kt = 0; kt < nk; ++kt) {
        uint4 ah0 = *(const uint4*)(aph + kt * 64);
        uint4 ah1 = *(const uint4*)(aph + kt * 64 + 8);
        uint4 ah2 = *(const uint4*)(aph + kt * 64 + 16);
        uint4 ah3 = *(const uint4*)(aph + kt * 64 + 24);
        uint4 al0 = *(const uint4*)(apl + kt * 64);
        uint4 al1 = *(const uint4*)(apl + kt * 64 + 8);
        uint4 al2 = *(const uint4*)(apl + kt * 64 + 16);
        uint4 al3 = *(const uint4*)(apl + kt * 64 + 24);
        uint4 bh0 = *(const uint4*)(bph + kt * 64);
        uint4 bh1 = *(const uint4*)(bph + kt * 64 + 8);
        uint4 bl0 = *(const uint4*)(bpl + kt * 64);
        uint4 bl1 = *(const uint4*)(bpl + kt * 64 + 8);

        __syncthreads();

        *(uint4*)&As_h[srow][skh] = ah0;
        *(uint4*)&As_h[srow][skh + 8] = ah1;
        *(uint4*)&As_h[srow][skh + 16] = ah2;
        *(uint4*)&As_h[srow][skh + 24] = ah3;
        *(uint4*)&As_l[srow][skh] = al0;
        *(uint4*)&As_l[srow][skh + 8] = al1;
        *(uint4*)&As_l[srow][skh + 16] = al2;
        *(uint4*)&As_l[srow][skh + 24] = al3;
        *(uint4*)&Bs_h[bn][bko] = bh0;
        *(uint4*)&Bs_h[bn][bko + 8] = bh1;
        *(uint4*)&Bs_l[bn][bko] = bl0;
        *(uint4*)&Bs_l[bn][bko + 8] = bl1;

        __syncthreads();

        #pragma unroll
        for (int ks = 0; ks < 2; ++ks) {
            const int ko = ks * 32 + fk;
            bf16x8 ah[2], al[2], bh[4], bl[4];
            #pragma unroll
            for (int m = 0; m < 2; ++m) {
                ah[m] = *(const bf16x8*)&As_h[wv * 32 + m * 16 + fr][ko];
                al[m] = *(const bf16x8*)&As_l[wv * 32 + m * 16 + fr][ko];
            }
            #pragma unroll
            for (int n = 0; n < 4; ++n) {
                bh[n] = *(const bf16x8*)&Bs_h[n * 16 + fr][ko];
                bl[n] = *(const bf16x8*)&Bs_l[n * 16 + fr][ko];
            }
            #pragma unroll
            for (int m = 0; m < 2; ++m)
                #pragma unroll
                for (int n = 0; n < 4; ++n) {
                    acc[m][n] = __builtin_amdgcn_mfma_f32_16x16x32_bf16(ah[m], bh[n], acc[m][n], 0, 0, 0);
                    acc[m][n] = __builtin_amdgcn_mfma_f32_16x16x32_bf16(ah[m], bl[n], acc[m][n], 0, 0, 0);
                    acc[m][n] = __builtin_amdgcn_mfma_f32_16x16x32_bf16(al[m], bh[n], acc[m][n], 0, 0, 0);
                }
        }
    }

    const int rbase = row0 + wv * 32 + (lane >> 4) * 4;
    if constexpr (OUTM == 3) {
        // fused per-row int16 quantization (ncb==1): row's Nc cols live in this wave's fr-group
        #pragma unroll
        for (int m = 0; m < 2; ++m) {
            #pragma unroll
            for (int j = 0; j < 4; ++j) {
                const int r = rbase + m * 16 + j;
                const int rr = (r < M) ? r : (M - 1);
                const float ds = dscale[rr];
                float vals[4];
                float mx = 0.f;
                #pragma unroll
                for (int n = 0; n < 4; ++n) {
                    float o = acc[m][n][j] * ds;
                    vals[n] = o;
                    mx = fmaxf(mx, fabsf(o));
                }
                mx = fmaxf(mx, __shfl_xor(mx, 1));
                mx = fmaxf(mx, __shfl_xor(mx, 2));
                mx = fmaxf(mx, __shfl_xor(mx, 4));
                mx = fmaxf(mx, __shfl_xor(mx, 8));
                float inv = (mx > 0.f) ? 32767.0f / mx : 0.f;
                if (r < M) {
                    short* C2 = (short*)Cv + (size_t)r * Nc;
                    #pragma unroll
                    for (int n = 0; n < 4; ++n)
                        C2[n * 16 + fr] = (short)__float2int_rn(vals[n] * inv);
                    if (fr == 0) qs_out[r] = mx * (1.0f / 32767.0f);
                }
            }
        }
        return;
    }

    float bv[4];
    #pragma unroll
    for (int n = 0; n < 4; ++n) bv[n] = BIAS ? bias[col0 + n * 16 + fr] : 0.f;
    #pragma unroll
    for (int m = 0; m < 2; ++m) {
        #pragma unroll
        for (int j = 0; j < 4; ++j) {
            const int r = rbase + m * 16 + j;
            if (r >= M) continue;
            float ds = 1.f;
            if constexpr (OUTM == 1) ds = dscale[r];
            #pragma unroll
            for (int n = 0; n < 4; ++n) {
                const int c = col0 + n * 16 + fr;
                float o = acc[m][n][j] + bv[n];
                if constexpr (RELU) o = fmaxf(o, 0.f);
                if constexpr (OUTM == 1) {
                    ((float*)Cv)[(size_t)r * Nc + c] = o * ds;
                } else {
                    unsigned short h = f2bf(o);
                    unsigned short l = f2bf(o - bf2f(h));
                    unsigned short* C2 = (unsigned short*)Cv + (size_t)r * 2 * Nc + c;
                    C2[0] = h;
                    C2[Nc] = l;
                }
            }
        }
    }
}

// ---------------- conditional softmax over 64 classes ----------------

__global__ __launch_bounds__(256) void k_softmax(float* __restrict__ out, const int* __restrict__ mode, int n) {
    if (*mode == 1) return;
    int lane = threadIdx.x & 63;
    int i = blockIdx.x * 4 + (threadIdx.x >> 6);
    if (i >= n) return;
    float v = out[(size_t)i * 64 + lane];
    float m = v;
    #pragma unroll
    for (int off = 32; off > 0; off >>= 1) m = fmaxf(m, __shfl_xor(m, off));
    float e = __expf(v - m);
    float s = e;
    #pragma unroll
    for (int off = 32; off > 0; off >>= 1) s += __shfl_xor(s, off);
    out[(size_t)i * 64 + lane] = e / s;
}

// ---------------- launch ----------------

extern "C" void kernel_launch(void* const* d_in, const int* in_sizes, int n_in,
                              void* d_out, int out_size, void* d_ws, size_t ws_size,
                              hipStream_t stream) {
    const float* x   = (const float*)d_in[0];
    const float* W1  = (const float*)d_in[1];
    const float* b1  = (const float*)d_in[2];
    const float* W2  = (const float*)d_in[3];
    const float* b2  = (const float*)d_in[4];
    const float* L1w = (const float*)d_in[5];
    const float* L1b = (const float*)d_in[6];
    const float* L2w = (const float*)d_in[7];
    const float* L2b = (const float*)d_in[8];
    const float* W3  = (const float*)d_in[9];
    const float* b3  = (const float*)d_in[10];
    const int* adj   = (const int*)d_in[11];
    const int* adj2  = (const int*)d_in[12];
    const int* mode  = (const int*)d_in[13];
    float* out = (float*)d_out;

    char* ws = (char*)d_ws;
    auto alloc = [&](size_t bytes) {
        char* p = ws;
        ws += (bytes + 255) & ~(size_t)255;
        return p;
    };
    char*  bufA  = alloc((size_t)NNODES * 256 * 4);   // 51.2 MB
    char*  bufB  = alloc((size_t)NNODES * 256 * 4);   // 51.2 MB
    int*   rp1   = (int*)alloc((NNODES + 1) * 4);
    int*   col1  = (int*)alloc((size_t)NEDGES * 4);
    int*   rp2   = (int*)alloc((NNODES + 1) * 4);
    int*   col2  = (int*)alloc((size_t)NEDGES * 4);
    float* dinv1 = (float*)alloc(NNODES * 4);
    float* dinv2 = (float*)alloc(NNODES * 4);
    int*   bcnt  = (int*)alloc(2 * NBKT * 4);
    int*   bbase = (int*)alloc(2 * NBKT * 4);
    float* qsA   = (float*)alloc(NNODES * 4);
    float* qsB   = (float*)alloc(NNODES * 4);
    signed char* B1h = (signed char*)alloc(256 * D_IN);
    signed char* B1l = (signed char*)alloc(256 * D_IN);
    signed char* B2h = (signed char*)alloc(256 * D_H);
    signed char* B2l = (signed char*)alloc(256 * D_H);
    float* ws1 = (float*)alloc(256 * 4);
    float* ws2 = (float*)alloc(256 * 4);
    unsigned short* L1h = (unsigned short*)alloc(D_H * D_IN * 2);
    unsigned short* L1l = (unsigned short*)alloc(D_H * D_IN * 2);
    unsigned short* L2h = (unsigned short*)alloc(D_IN * D_H * 2);
    unsigned short* L2l = (unsigned short*)alloc(D_IN * D_H * 2);
    unsigned short* W3h = (unsigned short*)alloc(D_H * D_OUT * 2);
    unsigned short* W3l = (unsigned short*)alloc(D_H * D_OUT * 2);
    unsigned* binned = (unsigned*)bufA;   // aliases bufA (consumed before bufA's first write)

    const int AGB = (NNODES + 3) / 4;
    const int MT = (NNODES + 127) / 128;
    const int BINB = (NEDGES + CHUNK - 1) / CHUNK;    // 391

    // weight preconversion
    k_wconv_all<<<(81920 + 255) / 256, 256, 0, stream>>>(L1w, L2w, W3,
        L1h, L1l, L2h, L2l, W3h, W3l);
    k_wconv_i8<<<128, 256, 0, stream>>>(W1, W2, B1h, B1l, B2h, B2l, ws1, ws2);

    // CSR build
    hipMemsetAsync(bcnt, 0, 2 * NBKT * 4, stream);
    k_bin<<<dim3(BINB, 2), 256, 0, stream>>>(adj, adj2, bcnt, binned, NEDGES);
    k_bktscan<<<1, 256, 0, stream>>>(bcnt, bbase, rp1, rp2);
    k_csr_bucket<<<dim3(NBKT, 2), 256, 0, stream>>>(binned, bcnt, bbase, rp1, rp2,
                                                    dinv1, dinv2, col1, col2, NNODES);

    // q(x .* dinv1) -> bufA int16 + qsA
    k_quant<128, true><<<AGB, 256, 0, stream>>>(x, dinv1, (short*)bufA, qsA, NNODES);
    // conv1 agg: bufA(q128, qsA) -> bufB i8 planes + qsB
    k_agg3<128, 0><<<AGB, 256, 0, stream>>>((const short*)bufA, qsA, rp1, col1, dinv1, nullptr, bufB, qsB, NNODES);
    // conv1 gemm (i8): relu((.)W1+b1) * dinv2 -> bufA (f32,256)
    k_gemm_i8<true, true, 1><<<MT * 4, 256, 0, stream>>>(
        (const unsigned char*)bufB, qsB, B1h, B1l, ws1, b1, dinv2, bufA, NNODES, D_IN, D_H, 4);
    // quantize: bufA(f32,256) -> bufB int16 + qsA
    k_quant<256, false><<<AGB, 256, 0, stream>>>((const float*)bufA, nullptr, (short*)bufB, qsA, NNODES);
    // conv2 agg: bufB(q256, qsA) -> bufA i8 planes + qsB
    k_agg3<256, 0><<<AGB, 256, 0, stream>>>((const short*)bufB, qsA, rp2, col2, dinv2, nullptr, bufA, qsB, NNODES);
    // conv2 gemm (i8): relu((.)W2+b2) -> bufB (hl,256)
    k_gemm_i8<true, true, 2><<<MT * 4, 256, 0, stream>>>(
        (const unsigned char*)bufA, qsB, B2h, B2l, ws2, b2, nullptr, bufB, NNODES, D_H, D_H, 4);
    // L1: relu((.)L1w+b) -> bufA (hl,128)
    k_gemm3<true, true, 2><<<MT * 2, 256, 0, stream>>>(
        (const unsigned short*)bufB, L1h, L1l, L1b, nullptr, bufA, nullptr, NNODES, D_H, D_IN, 2);
    // L2: relu((.)L2w+b) -> bufB (hl,256)
    k_gemm3<true, true, 2><<<MT * 4, 256, 0, stream>>>(
        (const unsigned short*)bufA, L2h, L2l, L2b, nullptr, bufB, nullptr, NNODES, D_IN, D_H, 4);
    // conv3 gemm: ((.)W3) * dinv2 -> bufA (int16 q64) + qsA  [fused quant, ncb=1]
    k_gemm3<false, false, 3><<<MT * 1, 256, 0, stream>>>(
        (const unsigned short*)bufB, W3h, W3l, nullptr, dinv2, bufA, qsA, NNODES, D_H, D_OUT, 1);
    // conv3 agg: bufA(q64, qsA) -> out (f32 + b3)
    k_agg3<64, 1><<<AGB, 256, 0, stream>>>((const short*)bufA, qsA, rp2, col2, dinv2, b3, out, nullptr, NNODES);
    // optional softmax (mode != 1)
    k_softmax<<<AGB, 256, 0, stream>>>(out, mode, NNODES);
}

// Round 13
// 323.972 us; speedup vs baseline: 1.0921x; 1.0072x over previous
//
#include <hip/hip_runtime.h>
#include <hip/hip_bf16.h>
#include <cstdint>
#include <cstddef>

#define NNODES 50000
#define NEDGES 800000
#define D_IN   128
#define D_H    256
#define D_OUT  64
#define BSH    9
#define BKN    (1 << BSH)                             // 512 nodes per bucket
#define NBKT   ((NNODES + BKN - 1) / BKN)             // 98
#define MAXB   12288                                  // cap per bucket (45 sigma)
#define CHUNK  2048
#define QMAX   32639.0f                               // 127*256+127: i8-splittable int16 range

typedef __attribute__((ext_vector_type(8))) short bf16x8;
typedef __attribute__((ext_vector_type(4))) float f32x4;
typedef __attribute__((ext_vector_type(4))) int   i32x4;

__device__ __forceinline__ unsigned short f2bf(float f) {
    unsigned u = __builtin_bit_cast(unsigned, f);
    unsigned r = (u + 0x7FFFu + ((u >> 16) & 1u)) >> 16;
    return (unsigned short)r;
}
__device__ __forceinline__ float bf2f(unsigned short h) {
    unsigned u = ((unsigned)h) << 16;
    return __builtin_bit_cast(float, u);
}

// ---------------- CSR build: bin -> bucket scan -> fused per-bucket CSR ----------------

__global__ __launch_bounds__(256) void k_bin(const int* __restrict__ adjA, const int* __restrict__ adjB,
                                             int* __restrict__ bcnt, unsigned* __restrict__ binned, int e) {
    __shared__ int h[NBKT], pfx[NBKT], put[NBKT], gbase[NBKT];
    __shared__ unsigned stage[CHUNK];
    const int g = blockIdx.y;
    const int* srcp = g ? adjB : adjA;
    const int* dstp = srcp + e;
    unsigned* outp = binned + (size_t)g * NBKT * MAXB;
    int* bc = bcnt + g * NBKT;
    const int tid = threadIdx.x;
    const int base = blockIdx.x * CHUNK;
    const int nrem = min(CHUNK, e - base);
    if (nrem <= 0) return;

    for (int t = tid; t < NBKT; t += 256) { h[t] = 0; put[t] = 0; }
    __syncthreads();

    unsigned pv[8];
    int bv[8];
    #pragma unroll
    for (int q = 0; q < 8; ++q) {
        int i = base + q * 256 + tid;
        bv[q] = -1;
        if (i < e) {
            int s = srcp[i];
            int d = dstp[i];
            pv[q] = ((unsigned)d << 16) | (unsigned)s;
            bv[q] = d >> BSH;
            atomicAdd(&h[bv[q]], 1);
        }
    }
    __syncthreads();
    if (tid == 0) {
        int r = 0;
        for (int k = 0; k < NBKT; ++k) { pfx[k] = r; r += h[k]; }
    }
    __syncthreads();
    #pragma unroll
    for (int q = 0; q < 8; ++q) {
        if (bv[q] >= 0) {
            int p = pfx[bv[q]] + atomicAdd(&put[bv[q]], 1);
            stage[p] = pv[q];
        }
    }
    __syncthreads();
    if (tid < NBKT && h[tid] > 0) gbase[tid] = atomicAdd(&bc[tid], h[tid]);
    __syncthreads();
    for (int idx = tid; idx < nrem; idx += 256) {
        unsigned v = stage[idx];
        int bb = v >> (16 + BSH);
        outp[(size_t)bb * MAXB + gbase[bb] + (idx - pfx[bb])] = v;
    }
}

__global__ void k_bktscan(const int* __restrict__ bcnt, int* __restrict__ bbase,
                          int* __restrict__ rp1, int* __restrict__ rp2) {
    __shared__ int s[2][NBKT];
    int t = threadIdx.x;
    if (t < NBKT) s[0][t] = bcnt[t];
    else if (t < 2 * NBKT) s[1][t - NBKT] = bcnt[t];
    __syncthreads();
    if (t < 2) {
        int r = 0;
        for (int k = 0; k < NBKT; ++k) { int v = s[t][k]; s[t][k] = r; r += v; }
    }
    __syncthreads();
    if (t < NBKT) bbase[t] = s[0][t];
    else if (t < 2 * NBKT) bbase[t] = s[1][t - NBKT];
    if (t == 0) { rp1[NNODES] = NEDGES; rp2[NNODES] = NEDGES; }
}

__global__ __launch_bounds__(256) void k_csr_bucket(const unsigned* __restrict__ binned,
                                                    const int* __restrict__ bcnt, const int* __restrict__ bbase,
                                                    int* __restrict__ rp1, int* __restrict__ rp2,
                                                    float* __restrict__ dinv1, float* __restrict__ dinv2,
                                                    int* __restrict__ col1, int* __restrict__ col2, int n) {
    __shared__ int lc[BKN];
    __shared__ int loff[BKN];
    __shared__ int ps[256];
    __shared__ int srt[MAXB];
    const int g = blockIdx.y;
    const int b = blockIdx.x;
    const unsigned* in = binned + (size_t)g * NBKT * MAXB + (size_t)b * MAXB;
    int* rp = g ? rp2 : rp1;
    float* dinv = g ? dinv2 : dinv1;
    int* col = g ? col2 : col1;
    const int nb = bcnt[g * NBKT + b];
    const int base0 = bbase[g * NBKT + b];
    const int nodebase = b << BSH;
    const int tid = threadIdx.x;

    for (int t = tid; t < BKN; t += 256) lc[t] = 0;
    __syncthreads();
    for (int t = tid; t < nb; t += 256)
        atomicAdd(&lc[(in[t] >> 16) & (BKN - 1)], 1);
    __syncthreads();
    int c0 = lc[2 * tid], c1 = lc[2 * tid + 1];
    int pair = c0 + c1;
    int sum = pair;
    ps[tid] = pair;
    __syncthreads();
    #pragma unroll
    for (int off = 1; off < 256; off <<= 1) {
        int u = (tid >= off) ? ps[tid - off] : 0;
        __syncthreads();
        sum += u;
        ps[tid] = sum;
        __syncthreads();
    }
    int excl = sum - pair;
    loff[2 * tid] = excl;
    loff[2 * tid + 1] = excl + c0;
    __syncthreads();
    for (int t = tid; t < BKN; t += 256) {
        int node = nodebase + t;
        if (node < n) {
            rp[node] = base0 + loff[t];
            dinv[node] = rsqrtf((float)(lc[t] + 1));
        }
    }
    __syncthreads();
    for (int t = tid; t < nb; t += 256) {
        unsigned v = in[t];
        int pos = atomicAdd(&loff[(v >> 16) & (BKN - 1)], 1);
        srt[pos] = (int)(v & 0xFFFFu);
    }
    __syncthreads();
    for (int t = tid; t < nb; t += 256) col[base0 + t] = srt[t];
}

// ---------------- quantize: fp32 rows -> int16 rows + per-row scale ----------------

template<int F, bool PRESCALE>
__global__ __launch_bounds__(256) void k_quant(const float* __restrict__ in, const float* __restrict__ dscale,
                                               short* __restrict__ q, float* __restrict__ qs, int n) {
    constexpr int VPT = F / 64;
    const int lane = threadIdx.x & 63;
    const int i = blockIdx.x * 4 + (threadIdx.x >> 6);
    if (i >= n) return;
    float v[VPT];
    const float* p = in + (size_t)i * F + lane * VPT;
    if constexpr (VPT == 4) { float4 t = *(const float4*)p; v[0] = t.x; v[1] = t.y; v[2] = t.z; v[3] = t.w; }
    else if constexpr (VPT == 2) { float2 t = *(const float2*)p; v[0] = t.x; v[1] = t.y; }
    else v[0] = *p;
    if constexpr (PRESCALE) {
        float d = dscale[i];
        #pragma unroll
        for (int c = 0; c < VPT; ++c) v[c] *= d;
    }
    float m = 0.f;
    #pragma unroll
    for (int c = 0; c < VPT; ++c) m = fmaxf(m, fabsf(v[c]));
    #pragma unroll
    for (int off = 32; off > 0; off >>= 1) m = fmaxf(m, __shfl_xor(m, off));
    float inv = (m > 0.f) ? 32767.0f / m : 0.f;
    short* qp = q + (size_t)i * F + lane * VPT;
    if constexpr (VPT == 4) {
        short4 o;
        o.x = (short)__float2int_rn(v[0] * inv);
        o.y = (short)__float2int_rn(v[1] * inv);
        o.z = (short)__float2int_rn(v[2] * inv);
        o.w = (short)__float2int_rn(v[3] * inv);
        *(short4*)qp = o;
    } else if constexpr (VPT == 2) {
        short2 o;
        o.x = (short)__float2int_rn(v[0] * inv);
        o.y = (short)__float2int_rn(v[1] * inv);
        *(short2*)qp = o;
    } else {
        *qp = (short)__float2int_rn(v[0] * inv);
    }
    if (lane == 0) qs[i] = m * (1.0f / 32767.0f);
}

// ---------------- Aggregation over int16-quantized prescaled input ----------------
// QSB: scale blocks per row (1 = per-row scale, 4 = per-64-col scale at qs[j*4+cb]).
// OUTM 0: emit per-row-quantized i8 hi/lo planes (A8h | A8l, each [n][F]) + qs_out
// OUTM 1: fp32 + bias (final output)

template<int F, int OUTM, int QSB>
__global__ __launch_bounds__(256) void k_agg3(const short* __restrict__ q, const float* __restrict__ qs,
                                              const int* __restrict__ rp, const int* __restrict__ col,
                                              const float* __restrict__ dinv, const float* __restrict__ bias,
                                              void* __restrict__ outv, float* __restrict__ qs_out, int n) {
    constexpr int VPT = F / 64;
    const int lane = threadIdx.x & 63;
    const int i = blockIdx.x * 4 + (threadIdx.x >> 6);
    if (i >= n) return;
    const int cb = (QSB == 1) ? 0 : ((lane * VPT) >> 6);
    const short* ql = q + lane * VPT;
    float acc[VPT];
    #pragma unroll
    for (int c = 0; c < VPT; ++c) acc[c] = 0.f;

    int k = rp[i], end = rp[i + 1];

    auto body1 = [&](int j) {
        float s = qs[j * QSB + cb];
        const short* pj = ql + (size_t)j * F;
        if constexpr (VPT == 4) {
            short4 v = *(const short4*)pj;
            acc[0] += s * (float)v.x; acc[1] += s * (float)v.y;
            acc[2] += s * (float)v.z; acc[3] += s * (float)v.w;
        } else if constexpr (VPT == 2) {
            short2 v = *(const short2*)pj;
            acc[0] += s * (float)v.x; acc[1] += s * (float)v.y;
        } else {
            acc[0] += s * (float)(*pj);
        }
    };

    body1(i);  // self loop
    if constexpr (VPT == 4) {
        for (; k + 8 <= end; k += 8) {
            int j[8]; float s[8]; short4 v[8];
            #pragma unroll
            for (int u = 0; u < 8; ++u) j[u] = col[k + u];
            #pragma unroll
            for (int u = 0; u < 8; ++u) s[u] = qs[j[u] * QSB + cb];
            #pragma unroll
            for (int u = 0; u < 8; ++u) v[u] = *(const short4*)(ql + (size_t)j[u] * F);
            #pragma unroll
            for (int u = 0; u < 8; ++u) {
                acc[0] += s[u] * (float)v[u].x; acc[1] += s[u] * (float)v[u].y;
                acc[2] += s[u] * (float)v[u].z; acc[3] += s[u] * (float)v[u].w;
            }
        }
    } else if constexpr (VPT == 2) {
        for (; k + 8 <= end; k += 8) {
            int j[8]; float s[8]; short2 v[8];
            #pragma unroll
            for (int u = 0; u < 8; ++u) j[u] = col[k + u];
            #pragma unroll
            for (int u = 0; u < 8; ++u) s[u] = qs[j[u] * QSB + cb];
            #pragma unroll
            for (int u = 0; u < 8; ++u) v[u] = *(const short2*)(ql + (size_t)j[u] * F);
            #pragma unroll
            for (int u = 0; u < 8; ++u) {
                acc[0] += s[u] * (float)v[u].x; acc[1] += s[u] * (float)v[u].y;
            }
        }
    }
    for (; k + 4 <= end; k += 4) {
        int j0 = col[k], j1 = col[k + 1], j2 = col[k + 2], j3 = col[k + 3];
        float s0 = qs[j0 * QSB + cb], s1 = qs[j1 * QSB + cb];
        float s2 = qs[j2 * QSB + cb], s3 = qs[j3 * QSB + cb];
        if constexpr (VPT == 4) {
            short4 v0 = *(const short4*)(ql + (size_t)j0 * F);
            short4 v1 = *(const short4*)(ql + (size_t)j1 * F);
            short4 v2 = *(const short4*)(ql + (size_t)j2 * F);
            short4 v3 = *(const short4*)(ql + (size_t)j3 * F);
            acc[0] += s0 * (float)v0.x + s1 * (float)v1.x + s2 * (float)v2.x + s3 * (float)v3.x;
            acc[1] += s0 * (float)v0.y + s1 * (float)v1.y + s2 * (float)v2.y + s3 * (float)v3.y;
            acc[2] += s0 * (float)v0.z + s1 * (float)v1.z + s2 * (float)v2.z + s3 * (float)v3.z;
            acc[3] += s0 * (float)v0.w + s1 * (float)v1.w + s2 * (float)v2.w + s3 * (float)v3.w;
        } else if constexpr (VPT == 2) {
            short2 v0 = *(const short2*)(ql + (size_t)j0 * F);
            short2 v1 = *(const short2*)(ql + (size_t)j1 * F);
            short2 v2 = *(const short2*)(ql + (size_t)j2 * F);
            short2 v3 = *(const short2*)(ql + (size_t)j3 * F);
            acc[0] += s0 * (float)v0.x + s1 * (float)v1.x + s2 * (float)v2.x + s3 * (float)v3.x;
            acc[1] += s0 * (float)v0.y + s1 * (float)v1.y + s2 * (float)v2.y + s3 * (float)v3.y;
        } else {
            float v0 = (float)ql[(size_t)j0 * F];
            float v1 = (float)ql[(size_t)j1 * F];
            float v2 = (float)ql[(size_t)j2 * F];
            float v3 = (float)ql[(size_t)j3 * F];
            acc[0] += s0 * v0 + s1 * v1 + s2 * v2 + s3 * v3;
        }
    }
    for (; k < end; ++k) body1(col[k]);

    float di = dinv[i];
    if constexpr (OUTM == 0) {
        float vals[VPT];
        float m = 0.f;
        #pragma unroll
        for (int c = 0; c < VPT; ++c) { vals[c] = acc[c] * di; m = fmaxf(m, fabsf(vals[c])); }
        #pragma unroll
        for (int off = 32; off > 0; off >>= 1) m = fmaxf(m, __shfl_xor(m, off));
        float inv = (m > 0.f) ? QMAX / m : 0.f;
        unsigned ph = 0, pl = 0;
        #pragma unroll
        for (int c = 0; c < VPT; ++c) {
            int qv = __float2int_rn(vals[c] * inv);
            int ah = (qv + 128) >> 8;
            int al = qv - (ah << 8);
            ph |= (unsigned)(ah & 0xFF) << (8 * c);
            pl |= (unsigned)(al & 0xFF) << (8 * c);
        }
        unsigned char* o8h = (unsigned char*)outv;
        unsigned char* o8l = o8h + (size_t)n * F;
        if constexpr (VPT == 4) {
            *(unsigned*)(o8h + (size_t)i * F + lane * 4) = ph;
            *(unsigned*)(o8l + (size_t)i * F + lane * 4) = pl;
        } else if constexpr (VPT == 2) {
            *(unsigned short*)(o8h + (size_t)i * F + lane * 2) = (unsigned short)ph;
            *(unsigned short*)(o8l + (size_t)i * F + lane * 2) = (unsigned short)pl;
        } else {
            o8h[(size_t)i * F + lane] = (unsigned char)ph;
            o8l[(size_t)i * F + lane] = (unsigned char)pl;
        }
        if (lane == 0) qs_out[i] = m * (1.0f / QMAX);
    } else {
        float* o = (float*)outv + (size_t)i * F + lane * VPT;
        #pragma unroll
        for (int c = 0; c < VPT; ++c) o[c] = acc[c] * di + bias[lane * VPT + c];
    }
}

// ---------------- weight preconvert: bf16 hi/lo path (L1w, L2w, W3) ----------------

__device__ __forceinline__ void wconv1(const float* __restrict__ W, unsigned short* __restrict__ Th,
                                       unsigned short* __restrict__ Tl, int idx, int K, int Nc) {
    int k = idx / Nc, n = idx - k * Nc;
    float v = W[idx];
    unsigned short h = f2bf(v);
    unsigned short l = f2bf(v - bf2f(h));
    Th[(size_t)n * K + k] = h;
    Tl[(size_t)n * K + k] = l;
}

__global__ void k_wconv_all(const float* L1w, const float* L2w, const float* W3,
                            unsigned short* L1h, unsigned short* L1l, unsigned short* L2h, unsigned short* L2l,
                            unsigned short* W3h, unsigned short* W3l) {
    int idx = blockIdx.x * blockDim.x + threadIdx.x;
    if (idx < 32768)        wconv1(L1w, L1h, L1l, idx, D_H, D_IN);
    else if (idx < 65536)   wconv1(L2w, L2h, L2l, idx - 32768, D_IN, D_H);
    else if (idx < 81920)   wconv1(W3, W3h, W3l, idx - 65536, D_H, D_OUT);
}

// ---------------- weight preconvert: int16 per-col scale -> i8 hi/lo planes (W1, W2) ----------------

__global__ __launch_bounds__(256) void k_wconv_i8(const float* __restrict__ W1, const float* __restrict__ W2,
        signed char* __restrict__ B1h, signed char* __restrict__ B1l,
        signed char* __restrict__ B2h, signed char* __restrict__ B2l,
        float* __restrict__ ws1, float* __restrict__ ws2) {
    const int c4 = blockIdx.x * 4 + (threadIdx.x >> 6);
    const int lane = threadIdx.x & 63;
    const float* W; signed char *Bh, *Bl; float* ws; int K, c;
    if (c4 < 256) { W = W1; Bh = B1h; Bl = B1l; ws = ws1; K = D_IN; c = c4; }
    else          { W = W2; Bh = B2h; Bl = B2l; ws = ws2; K = D_H;  c = c4 - 256; }
    float m = 0.f;
    for (int k = lane; k < K; k += 64) m = fmaxf(m, fabsf(W[(size_t)k * D_H + c]));
    #pragma unroll
    for (int off = 32; off > 0; off >>= 1) m = fmaxf(m, __shfl_xor(m, off));
    float inv = (m > 0.f) ? QMAX / m : 0.f;
    for (int k = lane; k < K; k += 64) {
        int qv = __float2int_rn(W[(size_t)k * D_H + c] * inv);
        int ah = (qv + 128) >> 8;
        int al = qv - (ah << 8);
        Bh[(size_t)c * K + k] = (signed char)ah;
        Bl[(size_t)c * K + k] = (signed char)al;
    }
    if (lane == 0) ws[c] = m * (1.0f / QMAX);
}

// ---------------- i8 split MFMA GEMM (hh + cross terms; ll dropped: ~1.6e-5 rel) ----------------
// OUTM 1: fp32 * dscale[row]; OUTM 2: bf16 hi/lo planes; OUTM 4: int16 + per-(row,colblock) qs.

template<bool RELU, bool BIAS, int OUTM>
__global__ __launch_bounds__(256) void k_gemm_i8(const unsigned char* __restrict__ A8,
        const float* __restrict__ qsr,
        const signed char* __restrict__ B8h, const signed char* __restrict__ B8l,
        const float* __restrict__ wsc,
        const float* __restrict__ bias, const float* __restrict__ dscale,
        void* __restrict__ Cv, float* __restrict__ qs_out, int M, int K, int Nc, int ncb) {
    constexpr int PADB = 68;
    __shared__ unsigned char As_h[128][PADB];
    __shared__ unsigned char As_l[128][PADB];
    __shared__ unsigned char Bs_h[64][PADB];
    __shared__ unsigned char Bs_l[64][PADB];

    const int nwg = gridDim.x;
    const int b = blockIdx.x;
    const int q8 = nwg >> 3, r8 = nwg & 7;
    const int xcd = b & 7;
    const int swz = (xcd < r8 ? xcd * (q8 + 1) : r8 * (q8 + 1) + (xcd - r8) * q8) + (b >> 3);
    const int row0 = (swz / ncb) * 128;
    const int col0 = (swz % ncb) * 64;

    const int tid = threadIdx.x;
    const int lane = tid & 63;
    const int wv = tid >> 6;

    i32x4 acc_hh[2][4], acc_mm[2][4];
    #pragma unroll
    for (int m = 0; m < 2; ++m)
        #pragma unroll
        for (int n = 0; n < 4; ++n) {
            acc_hh[m][n] = (i32x4)(0);
            acc_mm[m][n] = (i32x4)(0);
        }

    const int srow = tid >> 1;
    const int skh = (tid & 1) * 32;
    int arow = row0 + srow;
    if (arow >= M) arow = M - 1;
    const unsigned char* aph = A8 + (size_t)arow * K + skh;
    const unsigned char* apl = aph + (size_t)M * K;

    const int bn = tid >> 2;
    const int bko = (tid & 3) * 16;
    const signed char* bph = B8h + (size_t)(col0 + bn) * K + bko;
    const signed char* bpl = B8l + (size_t)(col0 + bn) * K + bko;

    const int fr = lane & 15;
    const int fko = (lane >> 4) * 16;

    const int nk = K >> 6;
    for (int kt = 0; kt < nk; ++kt) {
        uint4 ah0 = *(const uint4*)(aph + kt * 64);
        uint4 ah1 = *(const uint4*)(aph + kt * 64 + 16);
        uint4 al0 = *(const uint4*)(apl + kt * 64);
        uint4 al1 = *(const uint4*)(apl + kt * 64 + 16);
        uint4 bh0 = *(const uint4*)(bph + kt * 64);
        uint4 bl0 = *(const uint4*)(bpl + kt * 64);

        __syncthreads();

        *(uint4*)&As_h[srow][skh] = ah0;
        *(uint4*)&As_h[srow][skh + 16] = ah1;
        *(uint4*)&As_l[srow][skh] = al0;
        *(uint4*)&As_l[srow][skh + 16] = al1;
        *(uint4*)&Bs_h[bn][bko] = bh0;
        *(uint4*)&Bs_l[bn][bko] = bl0;

        __syncthreads();

        i32x4 fah[2], fal[2], fbh[4], fbl[4];
        #pragma unroll
        for (int m = 0; m < 2; ++m) {
            fah[m] = *(const i32x4*)&As_h[wv * 32 + m * 16 + fr][fko];
            fal[m] = *(const i32x4*)&As_l[wv * 32 + m * 16 + fr][fko];
        }
        #pragma unroll
        for (int n = 0; n < 4; ++n) {
            fbh[n] = *(const i32x4*)&Bs_h[n * 16 + fr][fko];
            fbl[n] = *(const i32x4*)&Bs_l[n * 16 + fr][fko];
        }
        #pragma unroll
        for (int m = 0; m < 2; ++m)
            #pragma unroll
            for (int n = 0; n < 4; ++n) {
                acc_hh[m][n] = __builtin_amdgcn_mfma_i32_16x16x64_i8(fah[m], fbh[n], acc_hh[m][n], 0, 0, 0);
                acc_mm[m][n] = __builtin_amdgcn_mfma_i32_16x16x64_i8(fah[m], fbl[n], acc_mm[m][n], 0, 0, 0);
                acc_mm[m][n] = __builtin_amdgcn_mfma_i32_16x16x64_i8(fal[m], fbh[n], acc_mm[m][n], 0, 0, 0);
            }
    }

    float bv[4], wv_[4];
    #pragma unroll
    for (int n = 0; n < 4; ++n) {
        const int c = col0 + n * 16 + fr;
        bv[n] = BIAS ? bias[c] : 0.f;
        wv_[n] = wsc[c];
    }
    const int rbase = row0 + wv * 32 + (lane >> 4) * 4;

    if constexpr (OUTM == 4) {
        // fused per-(row, colblock) int16 quantization
        #pragma unroll
        for (int m = 0; m < 2; ++m) {
            #pragma unroll
            for (int j = 0; j < 4; ++j) {
                const int r = rbase + m * 16 + j;
                const int rr = (r < M) ? r : (M - 1);
                const float qr = qsr[rr];
                const float ds = dscale[rr];
                float vals[4];
                float mx = 0.f;
                #pragma unroll
                for (int n = 0; n < 4; ++n) {
                    float dot = 65536.f * (float)acc_hh[m][n][j] + 256.f * (float)acc_mm[m][n][j];
                    float o = dot * qr * wv_[n] + bv[n];
                    if constexpr (RELU) o = fmaxf(o, 0.f);
                    o *= ds;
                    vals[n] = o;
                    mx = fmaxf(mx, fabsf(o));
                }
                mx = fmaxf(mx, __shfl_xor(mx, 1));
                mx = fmaxf(mx, __shfl_xor(mx, 2));
                mx = fmaxf(mx, __shfl_xor(mx, 4));
                mx = fmaxf(mx, __shfl_xor(mx, 8));
                float inv = (mx > 0.f) ? 32767.0f / mx : 0.f;
                if (r < M) {
                    short* C2 = (short*)Cv + (size_t)r * Nc + col0;
                    #pragma unroll
                    for (int n = 0; n < 4; ++n)
                        C2[n * 16 + fr] = (short)__float2int_rn(vals[n] * inv);
                    if (fr == 0) qs_out[(size_t)r * ncb + (col0 >> 6)] = mx * (1.0f / 32767.0f);
                }
            }
        }
        return;
    }

    #pragma unroll
    for (int m = 0; m < 2; ++m) {
        #pragma unroll
        for (int j = 0; j < 4; ++j) {
            const int r = rbase + m * 16 + j;
            if (r >= M) continue;
            const float qr = qsr[r];
            float ds = 1.f;
            if constexpr (OUTM == 1) ds = dscale[r];
            #pragma unroll
            for (int n = 0; n < 4; ++n) {
                const int c = col0 + n * 16 + fr;
                float dot = 65536.f * (float)acc_hh[m][n][j] + 256.f * (float)acc_mm[m][n][j];
                float o = dot * qr * wv_[n] + bv[n];
                if constexpr (RELU) o = fmaxf(o, 0.f);
                if constexpr (OUTM == 1) {
                    ((float*)Cv)[(size_t)r * Nc + c] = o * ds;
                } else {
                    unsigned short h = f2bf(o);
                    unsigned short l = f2bf(o - bf2f(h));
                    unsigned short* C2 = (unsigned short*)Cv + (size_t)r * 2 * Nc + c;
                    C2[0] = h;
                    C2[Nc] = l;
                }
            }
        }
    }
}

// ---------------- bf16x3 MFMA GEMM (L1, L2, W3) ----------------
// OUTM 1: fp32 * dscale; OUTM 2: bf16 hi/lo planes; OUTM 3: int16 + per-row qs (ncb==1).

template<bool RELU, bool BIAS, int OUTM>
__global__ __launch_bounds__(256) void k_gemm3(const unsigned short* __restrict__ Ahl,
        const unsigned short* __restrict__ Bth, const unsigned short* __restrict__ Btl,
        const float* __restrict__ bias, const float* __restrict__ dscale,
        void* __restrict__ Cv, float* __restrict__ qs_out, int M, int K, int Nc, int ncb) {
    constexpr int PAD = 66;
    __shared__ unsigned short As_h[128][PAD];
    __shared__ unsigned short As_l[128][PAD];
    __shared__ unsigned short Bs_h[64][PAD];
    __shared__ unsigned short Bs_l[64][PAD];

    const int nwg = gridDim.x;
    const int b = blockIdx.x;
    const int q8 = nwg >> 3, r8 = nwg & 7;
    const int xcd = b & 7;
    const int swz = (xcd < r8 ? xcd * (q8 + 1) : r8 * (q8 + 1) + (xcd - r8) * q8) + (b >> 3);
    const int row0 = (swz / ncb) * 128;
    const int col0 = (swz % ncb) * 64;

    const int tid = threadIdx.x;
    const int lane = tid & 63;
    const int wv = tid >> 6;

    f32x4 acc[2][4];
    #pragma unroll
    for (int m = 0; m < 2; ++m)
        #pragma unroll
        for (int n = 0; n < 4; ++n) acc[m][n] = (f32x4)(0.f);

    const int srow = tid >> 1;
    const int skh = (tid & 1) * 32;
    int arow = row0 + srow;
    if (arow >= M) arow = M - 1;
    const unsigned short* aph = Ahl + (size_t)arow * 2 * K + skh;
    const unsigned short* apl = aph + K;

    const int bn = tid >> 2;
    const int bko = (tid & 3) * 16;
    const unsigned short* bph = Bth + (size_t)(col0 + bn) * K + bko;
    const unsigned short* bpl = Btl + (size_t)(col0 + bn) * K + bko;

    const int fr = lane & 15;
    const int fk = (lane >> 4) * 8;

    const int nk = K >> 6;
    for (int kt = 0; kt < nk; ++kt) {
        uint4 ah0 = *(const uint4*)(aph + kt * 64);
        uint4 ah1 = *(const uint4*)(aph + kt * 64 + 8);
        uint4 ah2 = *(const uint4*)(aph + kt * 64 + 16);
        uint4 ah3 = *(const uint4*)(aph + kt * 64 + 24);
        uint4 al0 = *(const uint4*)(apl + kt * 64);
        uint4 al1 = *(const uint4*)(apl + kt * 64 + 8);
        uint4 al2 = *(const uint4*)(apl + kt * 64 + 16);
        uint4 al3 = *(const uint4*)(apl + kt * 64 + 24);
        uint4 bh0 = *(const uint4*)(bph + kt * 64);
        uint4 bh1 = *(const uint4*)(bph + kt * 64 + 8);
        uint4 bl0 = *(const uint4*)(bpl + kt * 64);
        uint4 bl1 = *(const uint4*)(bpl + kt * 64 + 8);

        __syncthreads();

        *(uint4*)&As_h[srow][skh] = ah0;
        *(uint4*)&As_h[srow][skh + 8] = ah1;
        *(uint4*)&As_h[srow][skh + 16] = ah2;
        *(uint4*)&As_h[srow][skh + 24] = ah3;
        *(uint4*)&As_l[srow][skh] = al0;
        *(uint4*)&As_l[srow][skh + 8] = al1;
        *(uint4*)&As_l[srow][skh + 16] = al2;
        *(uint4*)&As_l[srow][skh + 24] = al3;
        *(uint4*)&Bs_h[bn][bko] = bh0;
        *(uint4*)&Bs_h[bn][bko + 8] = bh1;
        *(uint4*)&Bs_l[bn][bko] = bl0;
        *(uint4*)&Bs_l[bn][bko + 8] = bl1;

        __syncthreads();

        #pragma unroll
        for (int ks = 0; ks < 2; ++ks) {
            const int ko = ks * 32 + fk;
            bf16x8 ah[2], al[2], bh[4], bl[4];
            #pragma unroll
            for (int m = 0; m < 2; ++m) {
                ah[m] = *(const bf16x8*)&As_h[wv * 32 + m * 16 + fr][ko];
                al[m] = *(const bf16x8*)&As_l[wv * 32 + m * 16 + fr][ko];
            }
            #pragma unroll
            for (int n = 0; n < 4; ++n) {
                bh[n] = *(const bf16x8*)&Bs_h[n * 16 + fr][ko];
                bl[n] = *(const bf16x8*)&Bs_l[n * 16 + fr][ko];
            }
            #pragma unroll
            for (int m = 0; m < 2; ++m)
                #pragma unroll
                for (int n = 0; n < 4; ++n) {
                    acc[m][n] = __builtin_amdgcn_mfma_f32_16x16x32_bf16(ah[m], bh[n], acc[m][n], 0, 0, 0);
                    acc[m][n] = __builtin_amdgcn_mfma_f32_16x16x32_bf16(ah[m], bl[n], acc[m][n], 0, 0, 0);
                    acc[m][n] = __builtin_amdgcn_mfma_f32_16x16x32_bf16(al[m], bh[n], acc[m][n], 0, 0, 0);
                }
        }
    }

    const int rbase = row0 + wv * 32 + (lane >> 4) * 4;
    if constexpr (OUTM == 3) {
        #pragma unroll
        for (int m = 0; m < 2; ++m) {
            #pragma unroll
            for (int j = 0; j < 4; ++j) {
                const int r = rbase + m * 16 + j;
                const int rr = (r < M) ? r : (M - 1);
                const float ds = dscale[rr];
                float vals[4];
                float mx = 0.f;
                #pragma unroll
                for (int n = 0; n < 4; ++n) {
                    float o = acc[m][n][j] * ds;
                    vals[n] = o;
                    mx = fmaxf(mx, fabsf(o));
                }
                mx = fmaxf(mx, __shfl_xor(mx, 1));
                mx = fmaxf(mx, __shfl_xor(mx, 2));
                mx = fmaxf(mx, __shfl_xor(mx, 4));
                mx = fmaxf(mx, __shfl_xor(mx, 8));
                float inv = (mx > 0.f) ? 32767.0f / mx : 0.f;
                if (r < M) {
                    short* C2 = (short*)Cv + (size_t)r * Nc;
                    #pragma unroll
                    for (int n = 0; n < 4; ++n)
                        C2[n * 16 + fr] = (short)__float2int_rn(vals[n] * inv);
                    if (fr == 0) qs_out[r] = mx * (1.0f / 32767.0f);
                }
            }
        }
        return;
    }

    float bv[4];
    #pragma unroll
    for (int n = 0; n < 4; ++n) bv[n] = BIAS ? bias[col0 + n * 16 + fr] : 0.f;
    #pragma unroll
    for (int m = 0; m < 2; ++m) {
        #pragma unroll
        for (int j = 0; j < 4; ++j) {
            const int r = rbase + m * 16 + j;
            if (r >= M) continue;
            float ds = 1.f;
            if constexpr (OUTM == 1) ds = dscale[r];
            #pragma unroll
            for (int n = 0; n < 4; ++n) {
                const int c = col0 + n * 16 + fr;
                float o = acc[m][n][j] + bv[n];
                if constexpr (RELU) o = fmaxf(o, 0.f);
                if constexpr (OUTM == 1) {
                    ((float*)Cv)[(size_t)r * Nc + c] = o * ds;
                } else {
                    unsigned short h = f2bf(o);
                    unsigned short l = f2bf(o - bf2f(h));
                    unsigned short* C2 = (unsigned short*)Cv + (size_t)r * 2 * Nc + c;
                    C2[0] = h;
                    C2[Nc] = l;
                }
            }
        }
    }
}

// ---------------- conditional softmax over 64 classes ----------------

__global__ __launch_bounds__(256) void k_softmax(float* __restrict__ out, const int* __restrict__ mode, int n) {
    if (*mode == 1) return;
    int lane = threadIdx.x & 63;
    int i = blockIdx.x * 4 + (threadIdx.x >> 6);
    if (i >= n) return;
    float v = out[(size_t)i * 64 + lane];
    float m = v;
    #pragma unroll
    for (int off = 32; off > 0; off >>= 1) m = fmaxf(m, __shfl_xor(m, off));
    float e = __expf(v - m);
    float s = e;
    #pragma unroll
    for (int off = 32; off > 0; off >>= 1) s += __shfl_xor(s, off);
    out[(size_t)i * 64 + lane] = e / s;
}

// ---------------- launch ----------------

extern "C" void kernel_launch(void* const* d_in, const int* in_sizes, int n_in,
                              void* d_out, int out_size, void* d_ws, size_t ws_size,
                              hipStream_t stream) {
    const float* x   = (const float*)d_in[0];
    const float* W1  = (const float*)d_in[1];
    const float* b1  = (const float*)d_in[2];
    const float* W2  = (const float*)d_in[3];
    const float* b2  = (const float*)d_in[4];
    const float* L1w = (const float*)d_in[5];
    const float* L1b = (const float*)d_in[6];
    const float* L2w = (const float*)d_in[7];
    const float* L2b = (const float*)d_in[8];
    const float* W3  = (const float*)d_in[9];
    const float* b3  = (const float*)d_in[10];
    const int* adj   = (const int*)d_in[11];
    const int* adj2  = (const int*)d_in[12];
    const int* mode  = (const int*)d_in[13];
    float* out = (float*)d_out;

    char* ws = (char*)d_ws;
    auto alloc = [&](size_t bytes) {
        char* p = ws;
        ws += (bytes + 255) & ~(size_t)255;
        return p;
    };
    char*  bufA  = alloc((size_t)NNODES * 256 * 4);   // 51.2 MB
    char*  bufB  = alloc((size_t)NNODES * 256 * 4);   // 51.2 MB
    int*   rp1   = (int*)alloc((NNODES + 1) * 4);
    int*   col1  = (int*)alloc((size_t)NEDGES * 4);
    int*   rp2   = (int*)alloc((NNODES + 1) * 4);
    int*   col2  = (int*)alloc((size_t)NEDGES * 4);
    float* dinv1 = (float*)alloc(NNODES * 4);
    float* dinv2 = (float*)alloc(NNODES * 4);
    int*   bcnt  = (int*)alloc(2 * NBKT * 4);
    int*   bbase = (int*)alloc(2 * NBKT * 4);
    float* qsA   = (float*)alloc(NNODES * 4);
    float* qsB   = (float*)alloc(NNODES * 4);
    float* qsA4  = (float*)alloc((size_t)NNODES * 4 * 4);   // per-(row, 64-colblock)
    signed char* B1h = (signed char*)alloc(256 * D_IN);
    signed char* B1l = (signed char*)alloc(256 * D_IN);
    signed char* B2h = (signed char*)alloc(256 * D_H);
    signed char* B2l = (signed char*)alloc(256 * D_H);
    float* ws1 = (float*)alloc(256 * 4);
    float* ws2 = (float*)alloc(256 * 4);
    unsigned short* L1h = (unsigned short*)alloc(D_H * D_IN * 2);
    unsigned short* L1l = (unsigned short*)alloc(D_H * D_IN * 2);
    unsigned short* L2h = (unsigned short*)alloc(D_IN * D_H * 2);
    unsigned short* L2l = (unsigned short*)alloc(D_IN * D_H * 2);
    unsigned short* W3h = (unsigned short*)alloc(D_H * D_OUT * 2);
    unsigned short* W3l = (unsigned short*)alloc(D_H * D_OUT * 2);
    unsigned* binned = (unsigned*)bufA;   // aliases bufA (consumed before bufA's first write)

    const int AGB = (NNODES + 3) / 4;
    const int MT = (NNODES + 127) / 128;
    const int BINB = (NEDGES + CHUNK - 1) / CHUNK;    // 391

    // weight preconversion
    k_wconv_all<<<(81920 + 255) / 256, 256, 0, stream>>>(L1w, L2w, W3,
        L1h, L1l, L2h, L2l, W3h, W3l);
    k_wconv_i8<<<128, 256, 0, stream>>>(W1, W2, B1h, B1l, B2h, B2l, ws1, ws2);

    // CSR build
    hipMemsetAsync(bcnt, 0, 2 * NBKT * 4, stream);
    k_bin<<<dim3(BINB, 2), 256, 0, stream>>>(adj, adj2, bcnt, binned, NEDGES);
    k_bktscan<<<1, 256, 0, stream>>>(bcnt, bbase, rp1, rp2);
    k_csr_bucket<<<dim3(NBKT, 2), 256, 0, stream>>>(binned, bcnt, bbase, rp1, rp2,
                                                    dinv1, dinv2, col1, col2, NNODES);

    // q(x .* dinv1) -> bufA int16 + qsA
    k_quant<128, true><<<AGB, 256, 0, stream>>>(x, dinv1, (short*)bufA, qsA, NNODES);
    // conv1 agg: bufA(q128, qsA) -> bufB i8 planes + qsB
    k_agg3<128, 0, 1><<<AGB, 256, 0, stream>>>((const short*)bufA, qsA, rp1, col1, dinv1, nullptr, bufB, qsB, NNODES);
    // conv1 gemm (i8): relu((.)W1+b1) * dinv2 -> bufA int16 q256 + qsA4  [fused per-colblock quant]
    k_gemm_i8<true, true, 4><<<MT * 4, 256, 0, stream>>>(
        (const unsigned char*)bufB, qsB, B1h, B1l, ws1, b1, dinv2, bufA, qsA4, NNODES, D_IN, D_H, 4);
    // conv2 agg: bufA(q256, qsA4) -> bufB i8 planes + qsB
    k_agg3<256, 0, 4><<<AGB, 256, 0, stream>>>((const short*)bufA, qsA4, rp2, col2, dinv2, nullptr, bufB, qsB, NNODES);
    // conv2 gemm (i8): relu((.)W2+b2) -> bufA (hl,256)
    k_gemm_i8<true, true, 2><<<MT * 4, 256, 0, stream>>>(
        (const unsigned char*)bufB, qsB, B2h, B2l, ws2, b2, nullptr, bufA, nullptr, NNODES, D_H, D_H, 4);
    // L1: relu((.)L1w+b) -> bufB (hl,128)
    k_gemm3<true, true, 2><<<MT * 2, 256, 0, stream>>>(
        (const unsigned short*)bufA, L1h, L1l, L1b, nullptr, bufB, nullptr, NNODES, D_H, D_IN, 2);
    // L2: relu((.)L2w+b) -> bufA (hl,256)
    k_gemm3<true, true, 2><<<MT * 4, 256, 0, stream>>>(
        (const unsigned short*)bufB, L2h, L2l, L2b, nullptr, bufA, nullptr, NNODES, D_IN, D_H, 4);
    // conv3 gemm: ((.)W3) * dinv2 -> bufB (int16 q64) + qsA  [fused quant, ncb=1]
    k_gemm3<false, false, 3><<<MT * 1, 256, 0, stream>>>(
        (const unsigned short*)bufA, W3h, W3l, nullptr, dinv2, bufB, qsA, NNODES, D_H, D_OUT, 1);
    // conv3 agg: bufB(q64, qsA) -> out (f32 + b3)
    k_agg3<64, 1, 1><<<AGB, 256, 0, stream>>>((const short*)bufB, qsA, rp2, col2, dinv2, b3, out, nullptr, NNODES);
    // optional softmax (mode != 1)
    k_softmax<<<AGB, 256, 0, stream>>>(out, mode, NNODES);
}